// Round 7
// baseline (463.856 us; speedup 1.0000x reference)
//
#include <hip/hip_runtime.h>
#include <cstdint>
#include <cstddef>

// Problem constants: B=4, T=2048, C=1024, H=16, d=64
#define T_SEQ 2048
#define CEMB  1024
#define NHEAD 16
#define DHEAD 64

// q pre-scale: 32 (sqrt(C) quirk) * log2(e)  -> logits in log2 units
#define QSCALE 46.1662413084468f

typedef __attribute__((ext_vector_type(8))) short bf16x8;
typedef __attribute__((ext_vector_type(4))) float f32x4;

static __device__ __forceinline__ unsigned short f2bf(float x) {
    unsigned u = __builtin_bit_cast(unsigned, x);
    unsigned r = (u + 0x7FFFu + ((u >> 16) & 1u)) >> 16;
    return (unsigned short)r;
}
static __device__ __forceinline__ float bf2f(unsigned short b) {
    unsigned u = ((unsigned)b) << 16;
    return __builtin_bit_cast(float, u);
}

// async global->LDS: 16B per lane; ldsbase wave-uniform, lane offset = lane*16B.
static __device__ __forceinline__ void gload16(const short* gsrc, short* ldsbase) {
    __builtin_amdgcn_global_load_lds(
        (const __attribute__((address_space(1))) void*)gsrc,
        (__attribute__((address_space(3))) void*)ldsbase, 16, 0, 0);
}

// ---------------------------------------------------------------------------
// MFMA GEMM, 128x128 tile, BK=32, 256 threads (4 waves, 2x2).
//   C[M][N] = A[M][K] @ B^T[N][K]^T + bias[N]
// SPLIT==3: A,B split hi/lo bf16, 3 MFMAs (hh+lh+hl) -> ~fp32 product.
// A_F32: A read fp32, split in staging. Else A bf16 via global_load_lds.
// OUT_MODE: 0 = fp32, 1 = bf16, 2 = split hi/lo bf16 (cols<1024 scaled QSCALE).
// ---------------------------------------------------------------------------
template<int SPLIT, bool A_F32, int OUT_MODE>
__global__ __launch_bounds__(256) void gemm_mfma_kernel(
    const float* __restrict__ Af, const short* __restrict__ Ah,
    const short* __restrict__ Bh, const short* __restrict__ Bl,
    const float* __restrict__ bias,
    void* __restrict__ Cout, void* __restrict__ Cout2, int K, int ldc)
{
    __shared__ __align__(16) short smem[(SPLIT == 3) ? 16384 : 8192];

    const int tid = threadIdx.x;
    const int w = tid >> 6, l = tid & 63;
    const int lr = l & 15, lg = l >> 4;
    const int wr = w >> 1, wc = w & 1;
    const int row0 = blockIdx.y * 128;
    const int col0 = blockIdx.x * 128;

    f32x4 acc[4][4];
    #pragma unroll
    for (int mt = 0; mt < 4; ++mt)
        #pragma unroll
        for (int nt = 0; nt < 4; ++nt)
            acc[mt][nt] = (f32x4){0.f, 0.f, 0.f, 0.f};

    const int sB0 = w * 128 + l, sB1 = sB0 + 64;
    const short* gB0 = Bh + (size_t)(col0 + (sB0 & 127)) * K + (sB0 >> 7) * 8;
    const short* gB1 = Bh + (size_t)(col0 + (sB1 & 127)) * K + (sB1 >> 7) * 8;
    short* dB0 = &smem[4096 + (w * 128) * 8];
    short* dB1 = &smem[4096 + (w * 128 + 64) * 8];
    const short* gBl0 = nullptr; const short* gBl1 = nullptr;
    if constexpr (SPLIT == 3) {
        gBl0 = Bl + (size_t)(col0 + (sB0 & 127)) * K + (sB0 >> 7) * 8;
        gBl1 = Bl + (size_t)(col0 + (sB1 & 127)) * K + (sB1 >> 7) * 8;
    }
    const short* gA0 = nullptr; const short* gA1 = nullptr;
    if constexpr (!A_F32) {
        gA0 = Ah + (size_t)(row0 + (sB0 & 127)) * K + (sB0 >> 7) * 8;
        gA1 = Ah + (size_t)(row0 + (sB1 & 127)) * K + (sB1 >> 7) * 8;
    }
    short* dA0 = &smem[(w * 128) * 8];
    short* dA1 = &smem[(w * 128 + 64) * 8];

    const int arow = tid >> 1, ahalf = tid & 1;
    const float* gAf = A_F32 ? (Af + (size_t)(row0 + arow) * K + ahalf * 16) : nullptr;

    for (int kt = 0; kt < K; kt += 32) {
        __syncthreads();
        if constexpr (!A_F32) {
            gload16(gA0 + kt, dA0);
            gload16(gA1 + kt, dA1);
        }
        gload16(gB0 + kt, dB0);
        gload16(gB1 + kt, dB1);
        if constexpr (SPLIT == 3) {
            gload16(gBl0 + kt, &smem[12288 + (w * 128) * 8]);
            gload16(gBl1 + kt, &smem[12288 + (w * 128 + 64) * 8]);
        }
        if constexpr (A_F32) {
            const float* src = gAf + kt;
            float4 f0 = *(const float4*)(src);
            float4 f1 = *(const float4*)(src + 4);
            float4 f2 = *(const float4*)(src + 8);
            float4 f3 = *(const float4*)(src + 12);
            float xs[16] = {f0.x, f0.y, f0.z, f0.w, f1.x, f1.y, f1.z, f1.w,
                            f2.x, f2.y, f2.z, f2.w, f3.x, f3.y, f3.z, f3.w};
            #pragma unroll
            for (int q = 0; q < 2; ++q) {
                bf16x8 h8, l8;
                #pragma unroll
                for (int e = 0; e < 8; ++e) {
                    float x = xs[q * 8 + e];
                    if constexpr (SPLIT == 3) {
                        unsigned u = __builtin_bit_cast(unsigned, x);
                        h8[e] = (short)(unsigned short)(u >> 16);
                        float hf = __builtin_bit_cast(float, u & 0xFFFF0000u);
                        l8[e] = (short)f2bf(x - hf);
                    } else {
                        h8[e] = (short)f2bf(x);
                    }
                }
                int slot = (ahalf * 2 + q) * 128 + arow;
                *(bf16x8*)&smem[slot * 8] = h8;
                if constexpr (SPLIT == 3) *(bf16x8*)&smem[8192 + slot * 8] = l8;
            }
        }
        __syncthreads();

        const int aoff = (lg * 128 + wr * 64 + lr) * 8;
        const int boff = 4096 + (lg * 128 + wc * 64 + lr) * 8;
        bf16x8 ahf[4], alf[4];
        #pragma unroll
        for (int mt = 0; mt < 4; ++mt) {
            ahf[mt] = *(const bf16x8*)&smem[aoff + mt * 128];
            if constexpr (SPLIT == 3)
                alf[mt] = *(const bf16x8*)&smem[8192 + aoff + mt * 128];
        }
        #pragma unroll
        for (int nt = 0; nt < 4; ++nt) {
            bf16x8 bhf = *(const bf16x8*)&smem[boff + nt * 128];
            if constexpr (SPLIT == 3) {
                bf16x8 blf = *(const bf16x8*)&smem[8192 + boff + nt * 128];
                #pragma unroll
                for (int mt = 0; mt < 4; ++mt) {
                    acc[mt][nt] = __builtin_amdgcn_mfma_f32_16x16x32_bf16(ahf[mt], bhf, acc[mt][nt], 0, 0, 0);
                    acc[mt][nt] = __builtin_amdgcn_mfma_f32_16x16x32_bf16(alf[mt], bhf, acc[mt][nt], 0, 0, 0);
                    acc[mt][nt] = __builtin_amdgcn_mfma_f32_16x16x32_bf16(ahf[mt], blf, acc[mt][nt], 0, 0, 0);
                }
            } else {
                #pragma unroll
                for (int mt = 0; mt < 4; ++mt)
                    acc[mt][nt] = __builtin_amdgcn_mfma_f32_16x16x32_bf16(ahf[mt], bhf, acc[mt][nt], 0, 0, 0);
            }
        }
    }

    #pragma unroll
    for (int mt = 0; mt < 4; ++mt) {
        #pragma unroll
        for (int r = 0; r < 4; ++r) {
            int m = row0 + wr * 64 + mt * 16 + lg * 4 + r;
            #pragma unroll
            for (int nt = 0; nt < 4; ++nt) {
                int n = col0 + wc * 64 + nt * 16 + lr;
                float v = acc[mt][nt][r] + bias[n];
                if constexpr (OUT_MODE == 0) {
                    ((float*)Cout)[(size_t)m * ldc + n] = v;
                } else if constexpr (OUT_MODE == 1) {
                    ((short*)Cout)[(size_t)m * ldc + n] = (short)f2bf(v);
                } else {
                    if (n < 1024) v *= QSCALE;
                    unsigned u = __builtin_bit_cast(unsigned, v);
                    ((short*)Cout)[(size_t)m * ldc + n] = (short)(unsigned short)(u >> 16);
                    float hf = __builtin_bit_cast(float, u & 0xFFFF0000u);
                    ((short*)Cout2)[(size_t)m * ldc + n] = (short)f2bf(v - hf);
                }
            }
        }
    }
}

// ---------------------------------------------------------------------------
// Transpose + hi/lo bf16 split: src fp32 [Krows][nsrc] -> hi/lo [N][1024]
// ---------------------------------------------------------------------------
__global__ __launch_bounds__(256) void transpose_split_kernel(
    const float* __restrict__ src, int nsrc,
    short* __restrict__ hi, short* __restrict__ lo)
{
    __shared__ float tile[64][68];
    const int tid = threadIdx.x;
    const int n0 = blockIdx.x * 64, k0 = blockIdx.y * 64;
    {
        int kr = tid >> 2, cg = tid & 3;
        const float* s = src + (size_t)(k0 + kr) * nsrc + n0 + cg * 16;
        #pragma unroll
        for (int q = 0; q < 4; ++q) {
            float4 f = *(const float4*)(s + q * 4);
            tile[kr][cg * 16 + q * 4 + 0] = f.x;
            tile[kr][cg * 16 + q * 4 + 1] = f.y;
            tile[kr][cg * 16 + q * 4 + 2] = f.z;
            tile[kr][cg * 16 + q * 4 + 3] = f.w;
        }
    }
    __syncthreads();
    {
        int nr = tid >> 2, kg = tid & 3;
        int n = n0 + nr;
        bf16x8 h0, h1, lo0, lo1;
        #pragma unroll
        for (int e = 0; e < 8; ++e) {
            float a = tile[kg * 16 + e][nr];
            float b = tile[kg * 16 + 8 + e][nr];
            unsigned short ha = f2bf(a), hb = f2bf(b);
            h0[e] = (short)ha; h1[e] = (short)hb;
            lo0[e] = (short)f2bf(a - bf2f(ha));
            lo1[e] = (short)f2bf(b - bf2f(hb));
        }
        short* dh = hi + (size_t)n * 1024 + k0 + kg * 16;
        *(bf16x8*)dh = h0;
        *(bf16x8*)(dh + 8) = h1;
        if (lo) {
            short* dl = lo + (size_t)n * 1024 + k0 + kg * 16;
            *(bf16x8*)dl = lo0;
            *(bf16x8*)(dl + 8) = lo1;
        }
    }
}

// ---------------------------------------------------------------------------
// Repack V: v bf16 [B*T][C] -> Vt bf16 [B][H][64][T]
// ---------------------------------------------------------------------------
__global__ __launch_bounds__(256) void repack_vt_kernel(
    const short* __restrict__ v, short* __restrict__ vt)
{
    __shared__ short tile[64][80];
    const int tid = threadIdx.x;
    const int tt = blockIdx.x, h = blockIdx.y, b = blockIdx.z;
    const int t0 = tt * 64;
    {
        int tr = tid >> 2, cgrp = tid & 3;
        const short* src = v + (size_t)(b * T_SEQ + t0 + tr) * CEMB + h * DHEAD + cgrp * 16;
        *(bf16x8*)&tile[tr][cgrp * 16]     = *(const bf16x8*)src;
        *(bf16x8*)&tile[tr][cgrp * 16 + 8] = *(const bf16x8*)(src + 8);
    }
    __syncthreads();
    {
        int d = tid >> 2, tc = tid & 3;
        short s[16];
        #pragma unroll
        for (int e = 0; e < 16; ++e) s[e] = tile[tc * 16 + e][d];
        short* dst = vt + ((size_t)((b * NHEAD + h) * DHEAD + d)) * T_SEQ + t0 + tc * 16;
        bf16x8 v0, v1;
        #pragma unroll
        for (int e = 0; e < 8; ++e) { v0[e] = s[e]; v1[e] = s[8 + e]; }
        *(bf16x8*)dst       = v0;
        *(bf16x8*)(dst + 8) = v1;
    }
}

// ---------------------------------------------------------------------------
// MFMA flash attention (causal). Inputs pre-split bf16:
//  - qkhi/qklo [B*T][2048]: q cols 0..1023 (pre-scaled by 32*log2e), k cols 1024..2047
//  - Vt bf16 [B][H][64][T]; output ctx bf16 [B*T][1024]
// ONE q-tile (128 rows) per block; grid 1024 = 16 tiles x 64 (b,h) = exactly
// 4 blocks/CU (all co-resident). Per-CU work balanced via the stride-256
// round-robin (R2-confirmed): CU cu gets xi set {g, 15-g, g^8, 15-(g^8)}
// (g = cu&15) -> exactly 68 KV-steps per CU.
// Single-buffered K/V LDS + per-rt Ps (32 KB total). Staging via
// global_load_lds with pre-swizzled source addresses. exp2-domain softmax
// with exact defer-rescale.
// ---------------------------------------------------------------------------
__global__ __launch_bounds__(256) void attn_mfma_kernel(
    const short* __restrict__ qkhi, const short* __restrict__ qklo,
    const short* __restrict__ vt, short* __restrict__ ctxb)
{
    // shorts: Khi @0 (4096), Klo @4096, Vs @8192, Ps @12288 (4096) = 32768 B
    __shared__ __align__(16) short smem[16384];

    const int tid = threadIdx.x;
    const int w = tid >> 6, l = tid & 63;
    const int lr = l & 15, lg = l >> 4;

    // balanced bid -> (xi, b, h) mapping
    const int bid = blockIdx.x;
    const int p  = bid >> 8;          // 0..3
    const int cu = bid & 255;
    const int g  = cu & 15;
    const int u  = cu >> 4;
    const int bh = (p << 4) | u;      // 0..63
    int xi = (p & 2) ? (g ^ 8) : g;
    if (p & 1) xi = 15 - xi;
    const int h = bh & 15, b = bh >> 4;
    const size_t bT = (size_t)b * T_SEQ;

    // staging granule geometry: issues i=0,1 -> granule g = w*128 + i*64 + l
    const int g0 = w * 128 + l, g1 = g0 + 64;
    const int rg0 = g0 >> 3, rg1 = g1 >> 3;                    // LDS row 0..63
    const int sc0 = (g0 & 7) ^ (rg0 & 7), sc1 = (g1 & 7) ^ (rg1 & 7);  // swizzled chunk
    short* const dst0 = &smem[(w * 128) * 8];
    short* const dst1 = &smem[(w * 128 + 64) * 8];

    // global source bases (row rg, swizzle-chunk sc pre-applied)
    const size_t koff0 = (bT + rg0) * 2048 + 1024 + h * DHEAD + sc0 * 8;
    const size_t koff1 = (bT + rg1) * 2048 + 1024 + h * DHEAD + sc1 * 8;
    const short* const pKh0 = qkhi + koff0;
    const short* const pKh1 = qkhi + koff1;
    const short* const pKl0 = qklo + koff0;
    const short* const pKl1 = qklo + koff1;
    const short* const pV0 = vt + ((size_t)((b * NHEAD + h) * DHEAD) + rg0) * T_SEQ + sc0 * 8;
    const short* const pV1 = vt + ((size_t)((b * NHEAD + h) * DHEAD) + rg1) * T_SEQ + sc1 * 8;

    const int q0 = xi * 128;
    const int qw = q0 + w * 32;

    // Q fragments: direct bf16 loads (pre-scaled, pre-split)
    bf16x8 ahi[2][2], alo[2][2];
    #pragma unroll
    for (int rt = 0; rt < 2; ++rt) {
        #pragma unroll
        for (int kk = 0; kk < 2; ++kk) {
            size_t off = (bT + qw + rt * 16 + lr) * 2048 + h * DHEAD + kk * 32 + lg * 8;
            ahi[rt][kk] = *(const bf16x8*)(qkhi + off);
            alo[rt][kk] = *(const bf16x8*)(qklo + off);
        }
    }

    f32x4 O[2][4];
    #pragma unroll
    for (int rt = 0; rt < 2; ++rt)
        #pragma unroll
        for (int dt = 0; dt < 4; ++dt)
            O[rt][dt] = (f32x4){0.f, 0.f, 0.f, 0.f};
    float mrun[2][4], lrun[2][4];
    #pragma unroll
    for (int rt = 0; rt < 2; ++rt)
        #pragma unroll
        for (int r = 0; r < 4; ++r) { mrun[rt][r] = -3.0e38f; lrun[rt][r] = 0.f; }

    const int nsteps = 2 * xi + 2;
    for (int t = 0; t < nsteps; ++t) {
        const int j0 = t * 64;
        __syncthreads();                 // prior-step readers done
        // stage K hi/lo + V for rows j0..j0+63 (pure DMA, no VALU)
        gload16(pKh0 + (size_t)j0 * 2048, dst0);
        gload16(pKh1 + (size_t)j0 * 2048, dst1);
        gload16(pKl0 + (size_t)j0 * 2048, dst0 + 4096);
        gload16(pKl1 + (size_t)j0 * 2048, dst1 + 4096);
        gload16(pV0 + j0, dst0 + 8192);
        gload16(pV1 + j0, dst1 + 8192);
        __syncthreads();                 // drains vmcnt -> tile ready

        #pragma unroll
        for (int rt = 0; rt < 2; ++rt) {
            if (j0 > qw + rt * 16 + 15) continue;   // fully masked rt-tile

            f32x4 S[4];
            #pragma unroll
            for (int ct = 0; ct < 4; ++ct) {
                f32x4 s = (f32x4){0.f, 0.f, 0.f, 0.f};
                #pragma unroll
                for (int kk = 0; kk < 2; ++kk) {
                    int j  = ct * 16 + lr;
                    int ck = kk * 4 + lg;
                    int idx = j * 64 + ((ck ^ (j & 7)) << 3);
                    bf16x8 bh8 = *(bf16x8*)&smem[idx];
                    bf16x8 bl8 = *(bf16x8*)&smem[4096 + idx];
                    s = __builtin_amdgcn_mfma_f32_16x16x32_bf16(ahi[rt][kk], bh8, s, 0, 0, 0);
                    s = __builtin_amdgcn_mfma_f32_16x16x32_bf16(alo[rt][kk], bh8, s, 0, 0, 0);
                    s = __builtin_amdgcn_mfma_f32_16x16x32_bf16(ahi[rt][kk], bl8, s, 0, 0, 0);
                }
                if (j0 + ct * 16 + 15 > qw + rt * 16) {
                    int jabs = j0 + ct * 16 + lr;
                    #pragma unroll
                    for (int r = 0; r < 4; ++r) {
                        int qabs = qw + rt * 16 + lg * 4 + r;
                        s[r] = (jabs <= qabs) ? s[r] : -3.0e38f;
                    }
                }
                S[ct] = s;
            }

            float tm[4];
            #pragma unroll
            for (int r = 0; r < 4; ++r) {
                float v = fmaxf(fmaxf(S[0][r], S[1][r]), fmaxf(S[2][r], S[3][r]));
                v = fmaxf(v, __shfl_xor(v, 1));
                v = fmaxf(v, __shfl_xor(v, 2));
                v = fmaxf(v, __shfl_xor(v, 4));
                v = fmaxf(v, __shfl_xor(v, 8));
                tm[r] = v;
            }
            bool exceed = (tm[0] > mrun[rt][0]) | (tm[1] > mrun[rt][1]) |
                          (tm[2] > mrun[rt][2]) | (tm[3] > mrun[rt][3]);
            if (__any(exceed)) {   // rescale pass (exact skip otherwise)
                #pragma unroll
                for (int r = 0; r < 4; ++r) {
                    float mnew  = fmaxf(mrun[rt][r], tm[r]);
                    float alpha = __builtin_amdgcn_exp2f(mrun[rt][r] - mnew);
                    mrun[rt][r] = mnew;
                    lrun[rt][r] *= alpha;
                    #pragma unroll
                    for (int dt = 0; dt < 4; ++dt)
                        O[rt][dt][r] *= alpha;
                }
            }

            // P = exp2(S - m) -> per-wave per-rt Ps region (16 rows)
            float lsum[4] = {0.f, 0.f, 0.f, 0.f};
            #pragma unroll
            for (int ct = 0; ct < 4; ++ct) {
                #pragma unroll
                for (int r = 0; r < 4; ++r) {
                    float pv = __builtin_amdgcn_exp2f(S[ct][r] - mrun[rt][r]);
                    lsum[r] += pv;
                    int row = lg * 4 + r;              // 0..15
                    int col = ct * 16 + lr;
                    smem[12288 + w * 1024 + row * 64 + (col ^ ((row & 7) << 3))] = (short)f2bf(pv);
                }
            }
            #pragma unroll
            for (int r = 0; r < 4; ++r) {
                float s = lsum[r];
                s += __shfl_xor(s, 1);
                s += __shfl_xor(s, 2);
                s += __shfl_xor(s, 4);
                s += __shfl_xor(s, 8);
                lrun[rt][r] += s;
            }

            __builtin_amdgcn_wave_barrier();  // order P writes before P reads

            // PV: O[rt] += P @ V
            bf16x8 pa[2];
            #pragma unroll
            for (int jk = 0; jk < 2; ++jk) {
                int ck = jk * 4 + lg;
                pa[jk] = *(bf16x8*)&smem[12288 + w * 1024 + lr * 64 + ((ck ^ (lr & 7)) << 3)];
            }
            #pragma unroll
            for (int dt = 0; dt < 4; ++dt) {
                #pragma unroll
                for (int jk = 0; jk < 2; ++jk) {
                    int d  = dt * 16 + lr;
                    int ck = jk * 4 + lg;
                    bf16x8 vb = *(bf16x8*)&smem[8192 + d * 64 + ((ck ^ (d & 7)) << 3)];
                    O[rt][dt] = __builtin_amdgcn_mfma_f32_16x16x32_bf16(pa[jk], vb, O[rt][dt], 0, 0, 0);
                }
            }
            __builtin_amdgcn_wave_barrier();  // PV reads done before next rt's writes
        }
    }

    #pragma unroll
    for (int rt = 0; rt < 2; ++rt) {
        #pragma unroll
        for (int r = 0; r < 4; ++r) {
            float inv = 1.0f / lrun[rt][r];
            int row = qw + rt * 16 + lg * 4 + r;
            #pragma unroll
            for (int dt = 0; dt < 4; ++dt) {
                int col = h * DHEAD + dt * 16 + lr;
                ctxb[(size_t)(b * T_SEQ + row) * CEMB + col] = (short)f2bf(O[rt][dt][r] * inv);
            }
        }
    }
}

// ---------------------------------------------------------------------------
extern "C" void kernel_launch(void* const* d_in, const int* in_sizes, int n_in,
                              void* d_out, int out_size, void* d_ws, size_t ws_size,
                              hipStream_t stream)
{
    const float* x    = (const float*)d_in[0];
    const float* Wqkv = (const float*)d_in[1];
    const float* bqkv = (const float*)d_in[2];
    const float* Wo   = (const float*)d_in[3];
    const float* bo   = (const float*)d_in[4];
    float* out = (float*)d_out;

    // Workspace (110 MB):
    char* ws = (char*)d_ws;
    short* qkhi = (short*)ws;                           // 32 MB [8192][2048] (late)
    short* vbuf = (short*)ws;                           // 16 MB [8192][1024] (early, dead before qk)
    short* qklo = (short*)(ws + (size_t)(32u << 20));   // 32 MB
    short* Vt   = (short*)(ws + (size_t)(64u << 20));   // 16 MB [B][H][64][T]
    short* ctxb = (short*)(ws + (size_t)(80u << 20));   // 16 MB [8192][1024]
    short* WhiT = (short*)(ws + (size_t)(96u << 20));   // 6 MB [3072][1024]
    short* WloT = (short*)(ws + (size_t)(102u << 20));  // 6 MB
    short* WoT  = (short*)(ws + (size_t)(108u << 20));  // 2 MB [1024][1024]

    // 1) weight transpose+split
    transpose_split_kernel<<<dim3(48, 16), 256, 0, stream>>>(Wqkv, 3 * CEMB, WhiT, WloT);
    transpose_split_kernel<<<dim3(16, 16), 256, 0, stream>>>(Wo, CEMB, WoT, nullptr);

    // 2) V = x @ Wv + bv  (bf16 out)
    gemm_mfma_kernel<1, true, 1><<<dim3(8, 64), 256, 0, stream>>>(
        x, nullptr, WhiT + (size_t)2048 * 1024, nullptr, bqkv + 2048, vbuf, nullptr, CEMB, CEMB);

    // 3) repack V -> Vt
    repack_vt_kernel<<<dim3(32, 16, 4), 256, 0, stream>>>(vbuf, Vt);

    // 4) qk = x @ Wqk + b  -> split hi/lo bf16, q cols pre-scaled (overwrites vbuf)
    gemm_mfma_kernel<3, true, 2><<<dim3(16, 64), 256, 0, stream>>>(
        x, nullptr, WhiT, WloT, bqkv, qkhi, qklo, CEMB, 2048);

    // 5) causal MFMA flash attention -> ctx bf16 (1024 balanced blocks)
    attn_mfma_kernel<<<dim3(1024), 256, 0, stream>>>(qkhi, qklo, Vt, ctxb);

    // 6) out = ctx @ Wo + bo  (fp32 out)
    gemm_mfma_kernel<1, false, 0><<<dim3(8, 64), 256, 0, stream>>>(
        nullptr, ctxb, WoT, nullptr, bo, out, nullptr, CEMB, CEMB);
}

// Round 8
// 384.537 us; speedup vs baseline: 1.2063x; 1.2063x over previous
//
#include <hip/hip_runtime.h>
#include <cstdint>
#include <cstddef>

// Problem constants: B=4, T=2048, C=1024, H=16, d=64
#define T_SEQ 2048
#define CEMB  1024
#define NHEAD 16
#define DHEAD 64

// q pre-scale: 32 (sqrt(C) quirk) * log2(e)  -> logits in log2 units
#define QSCALE 46.1662413084468f

typedef __attribute__((ext_vector_type(8))) short bf16x8;
typedef __attribute__((ext_vector_type(4))) float f32x4;

static __device__ __forceinline__ unsigned short f2bf(float x) {
    unsigned u = __builtin_bit_cast(unsigned, x);
    unsigned r = (u + 0x7FFFu + ((u >> 16) & 1u)) >> 16;
    return (unsigned short)r;
}
static __device__ __forceinline__ float bf2f(unsigned short b) {
    unsigned u = ((unsigned)b) << 16;
    return __builtin_bit_cast(float, u);
}

// async global->LDS: 16B per lane; ldsbase wave-uniform, lane offset = lane*16B.
static __device__ __forceinline__ void gload16(const short* gsrc, short* ldsbase) {
    __builtin_amdgcn_global_load_lds(
        (const __attribute__((address_space(1))) void*)gsrc,
        (__attribute__((address_space(3))) void*)ldsbase, 16, 0, 0);
}

// ---------------------------------------------------------------------------
// MFMA GEMM, 128x128 tile, BK=32, 256 threads (4 waves, 2x2).
//   C[M][N] = A[M][K] @ B^T[N][K]^T + bias[N]
// SPLIT==3: A,B split hi/lo bf16, 3 MFMAs (hh+lh+hl) -> ~fp32 product.
// A_F32: A read fp32, split in staging. Else A bf16 via global_load_lds.
// OUT_MODE: 0 = fp32, 1 = bf16, 2 = split hi/lo bf16 (cols<1024 scaled QSCALE).
// ---------------------------------------------------------------------------
template<int SPLIT, bool A_F32, int OUT_MODE>
__global__ __launch_bounds__(256) void gemm_mfma_kernel(
    const float* __restrict__ Af, const short* __restrict__ Ah,
    const short* __restrict__ Bh, const short* __restrict__ Bl,
    const float* __restrict__ bias,
    void* __restrict__ Cout, void* __restrict__ Cout2, int K, int ldc)
{
    __shared__ __align__(16) short smem[(SPLIT == 3) ? 16384 : 8192];

    const int tid = threadIdx.x;
    const int w = tid >> 6, l = tid & 63;
    const int lr = l & 15, lg = l >> 4;
    const int wr = w >> 1, wc = w & 1;
    const int row0 = blockIdx.y * 128;
    const int col0 = blockIdx.x * 128;

    f32x4 acc[4][4];
    #pragma unroll
    for (int mt = 0; mt < 4; ++mt)
        #pragma unroll
        for (int nt = 0; nt < 4; ++nt)
            acc[mt][nt] = (f32x4){0.f, 0.f, 0.f, 0.f};

    const int sB0 = w * 128 + l, sB1 = sB0 + 64;
    const short* gB0 = Bh + (size_t)(col0 + (sB0 & 127)) * K + (sB0 >> 7) * 8;
    const short* gB1 = Bh + (size_t)(col0 + (sB1 & 127)) * K + (sB1 >> 7) * 8;
    short* dB0 = &smem[4096 + (w * 128) * 8];
    short* dB1 = &smem[4096 + (w * 128 + 64) * 8];
    const short* gBl0 = nullptr; const short* gBl1 = nullptr;
    if constexpr (SPLIT == 3) {
        gBl0 = Bl + (size_t)(col0 + (sB0 & 127)) * K + (sB0 >> 7) * 8;
        gBl1 = Bl + (size_t)(col0 + (sB1 & 127)) * K + (sB1 >> 7) * 8;
    }
    const short* gA0 = nullptr; const short* gA1 = nullptr;
    if constexpr (!A_F32) {
        gA0 = Ah + (size_t)(row0 + (sB0 & 127)) * K + (sB0 >> 7) * 8;
        gA1 = Ah + (size_t)(row0 + (sB1 & 127)) * K + (sB1 >> 7) * 8;
    }
    short* dA0 = &smem[(w * 128) * 8];
    short* dA1 = &smem[(w * 128 + 64) * 8];

    const int arow = tid >> 1, ahalf = tid & 1;
    const float* gAf = A_F32 ? (Af + (size_t)(row0 + arow) * K + ahalf * 16) : nullptr;

    for (int kt = 0; kt < K; kt += 32) {
        __syncthreads();
        if constexpr (!A_F32) {
            gload16(gA0 + kt, dA0);
            gload16(gA1 + kt, dA1);
        }
        gload16(gB0 + kt, dB0);
        gload16(gB1 + kt, dB1);
        if constexpr (SPLIT == 3) {
            gload16(gBl0 + kt, &smem[12288 + (w * 128) * 8]);
            gload16(gBl1 + kt, &smem[12288 + (w * 128 + 64) * 8]);
        }
        if constexpr (A_F32) {
            const float* src = gAf + kt;
            float4 f0 = *(const float4*)(src);
            float4 f1 = *(const float4*)(src + 4);
            float4 f2 = *(const float4*)(src + 8);
            float4 f3 = *(const float4*)(src + 12);
            float xs[16] = {f0.x, f0.y, f0.z, f0.w, f1.x, f1.y, f1.z, f1.w,
                            f2.x, f2.y, f2.z, f2.w, f3.x, f3.y, f3.z, f3.w};
            #pragma unroll
            for (int q = 0; q < 2; ++q) {
                bf16x8 h8, l8;
                #pragma unroll
                for (int e = 0; e < 8; ++e) {
                    float x = xs[q * 8 + e];
                    if constexpr (SPLIT == 3) {
                        unsigned u = __builtin_bit_cast(unsigned, x);
                        h8[e] = (short)(unsigned short)(u >> 16);
                        float hf = __builtin_bit_cast(float, u & 0xFFFF0000u);
                        l8[e] = (short)f2bf(x - hf);
                    } else {
                        h8[e] = (short)f2bf(x);
                    }
                }
                int slot = (ahalf * 2 + q) * 128 + arow;
                *(bf16x8*)&smem[slot * 8] = h8;
                if constexpr (SPLIT == 3) *(bf16x8*)&smem[8192 + slot * 8] = l8;
            }
        }
        __syncthreads();

        const int aoff = (lg * 128 + wr * 64 + lr) * 8;
        const int boff = 4096 + (lg * 128 + wc * 64 + lr) * 8;
        bf16x8 ahf[4], alf[4];
        #pragma unroll
        for (int mt = 0; mt < 4; ++mt) {
            ahf[mt] = *(const bf16x8*)&smem[aoff + mt * 128];
            if constexpr (SPLIT == 3)
                alf[mt] = *(const bf16x8*)&smem[8192 + aoff + mt * 128];
        }
        #pragma unroll
        for (int nt = 0; nt < 4; ++nt) {
            bf16x8 bhf = *(const bf16x8*)&smem[boff + nt * 128];
            if constexpr (SPLIT == 3) {
                bf16x8 blf = *(const bf16x8*)&smem[8192 + boff + nt * 128];
                #pragma unroll
                for (int mt = 0; mt < 4; ++mt) {
                    acc[mt][nt] = __builtin_amdgcn_mfma_f32_16x16x32_bf16(ahf[mt], bhf, acc[mt][nt], 0, 0, 0);
                    acc[mt][nt] = __builtin_amdgcn_mfma_f32_16x16x32_bf16(alf[mt], bhf, acc[mt][nt], 0, 0, 0);
                    acc[mt][nt] = __builtin_amdgcn_mfma_f32_16x16x32_bf16(ahf[mt], blf, acc[mt][nt], 0, 0, 0);
                }
            } else {
                #pragma unroll
                for (int mt = 0; mt < 4; ++mt)
                    acc[mt][nt] = __builtin_amdgcn_mfma_f32_16x16x32_bf16(ahf[mt], bhf, acc[mt][nt], 0, 0, 0);
            }
        }
    }

    #pragma unroll
    for (int mt = 0; mt < 4; ++mt) {
        #pragma unroll
        for (int r = 0; r < 4; ++r) {
            int m = row0 + wr * 64 + mt * 16 + lg * 4 + r;
            #pragma unroll
            for (int nt = 0; nt < 4; ++nt) {
                int n = col0 + wc * 64 + nt * 16 + lr;
                float v = acc[mt][nt][r] + bias[n];
                if constexpr (OUT_MODE == 0) {
                    ((float*)Cout)[(size_t)m * ldc + n] = v;
                } else if constexpr (OUT_MODE == 1) {
                    ((short*)Cout)[(size_t)m * ldc + n] = (short)f2bf(v);
                } else {
                    if (n < 1024) v *= QSCALE;
                    unsigned u = __builtin_bit_cast(unsigned, v);
                    ((short*)Cout)[(size_t)m * ldc + n] = (short)(unsigned short)(u >> 16);
                    float hf = __builtin_bit_cast(float, u & 0xFFFF0000u);
                    ((short*)Cout2)[(size_t)m * ldc + n] = (short)f2bf(v - hf);
                }
            }
        }
    }
}

// ---------------------------------------------------------------------------
// Transpose + hi/lo bf16 split: src fp32 [Krows][nsrc] -> hi/lo [N][1024]
// ---------------------------------------------------------------------------
__global__ __launch_bounds__(256) void transpose_split_kernel(
    const float* __restrict__ src, int nsrc,
    short* __restrict__ hi, short* __restrict__ lo)
{
    __shared__ float tile[64][68];
    const int tid = threadIdx.x;
    const int n0 = blockIdx.x * 64, k0 = blockIdx.y * 64;
    {
        int kr = tid >> 2, cg = tid & 3;
        const float* s = src + (size_t)(k0 + kr) * nsrc + n0 + cg * 16;
        #pragma unroll
        for (int q = 0; q < 4; ++q) {
            float4 f = *(const float4*)(s + q * 4);
            tile[kr][cg * 16 + q * 4 + 0] = f.x;
            tile[kr][cg * 16 + q * 4 + 1] = f.y;
            tile[kr][cg * 16 + q * 4 + 2] = f.z;
            tile[kr][cg * 16 + q * 4 + 3] = f.w;
        }
    }
    __syncthreads();
    {
        int nr = tid >> 2, kg = tid & 3;
        int n = n0 + nr;
        bf16x8 h0, h1, lo0, lo1;
        #pragma unroll
        for (int e = 0; e < 8; ++e) {
            float a = tile[kg * 16 + e][nr];
            float b = tile[kg * 16 + 8 + e][nr];
            unsigned short ha = f2bf(a), hb = f2bf(b);
            h0[e] = (short)ha; h1[e] = (short)hb;
            lo0[e] = (short)f2bf(a - bf2f(ha));
            lo1[e] = (short)f2bf(b - bf2f(hb));
        }
        short* dh = hi + (size_t)n * 1024 + k0 + kg * 16;
        *(bf16x8*)dh = h0;
        *(bf16x8*)(dh + 8) = h1;
        if (lo) {
            short* dl = lo + (size_t)n * 1024 + k0 + kg * 16;
            *(bf16x8*)dl = lo0;
            *(bf16x8*)(dl + 8) = lo1;
        }
    }
}

// ---------------------------------------------------------------------------
// Repack V: v bf16 [B*T][C] -> Vt bf16 [B][H][64][T]
// ---------------------------------------------------------------------------
__global__ __launch_bounds__(256) void repack_vt_kernel(
    const short* __restrict__ v, short* __restrict__ vt)
{
    __shared__ short tile[64][80];
    const int tid = threadIdx.x;
    const int tt = blockIdx.x, h = blockIdx.y, b = blockIdx.z;
    const int t0 = tt * 64;
    {
        int tr = tid >> 2, cgrp = tid & 3;
        const short* src = v + (size_t)(b * T_SEQ + t0 + tr) * CEMB + h * DHEAD + cgrp * 16;
        *(bf16x8*)&tile[tr][cgrp * 16]     = *(const bf16x8*)src;
        *(bf16x8*)&tile[tr][cgrp * 16 + 8] = *(const bf16x8*)(src + 8);
    }
    __syncthreads();
    {
        int d = tid >> 2, tc = tid & 3;
        short s[16];
        #pragma unroll
        for (int e = 0; e < 16; ++e) s[e] = tile[tc * 16 + e][d];
        short* dst = vt + ((size_t)((b * NHEAD + h) * DHEAD + d)) * T_SEQ + t0 + tc * 16;
        bf16x8 v0, v1;
        #pragma unroll
        for (int e = 0; e < 8; ++e) { v0[e] = s[e]; v1[e] = s[8 + e]; }
        *(bf16x8*)dst       = v0;
        *(bf16x8*)(dst + 8) = v1;
    }
}

// ---------------------------------------------------------------------------
// MFMA flash attention (causal). Inputs pre-split bf16:
//  - qkhi/qklo [B*T][2048]: q cols 0..1023 (pre-scaled by 32*log2e), k cols 1024..2047
//  - Vt bf16 [B][H][64][T]; output ctx bf16 [B*T][1024]
// 64-row q-tiles over 32 tiles, paired (xi, 31-xi) -> EVERY block does exactly
// 33 KV-steps (work-uniform; no scheduler assumptions). Grid 1024 = 16 pairs x
// 64 (b,h), 4 blocks/CU all co-resident. bid = pair*64 + bh so bid%8 = bh%8:
// all blocks of one (b,h) share an XCD -> co-temporal K/V tile reads hit L2.
// Wave owns 16 q-rows. LDS 32 KB: Khi/Klo/Vs 8 KB each + Ps 8 KB.
// Staging via global_load_lds with pre-swizzled source addresses.
// exp2-domain softmax with exact defer-rescale.
// ---------------------------------------------------------------------------
__global__ __launch_bounds__(256) void attn_mfma_kernel(
    const short* __restrict__ qkhi, const short* __restrict__ qklo,
    const short* __restrict__ vt, short* __restrict__ ctxb)
{
    // shorts: Khi @0 (4096), Klo @4096, Vs @8192, Ps @12288 (4096) = 32768 B
    __shared__ __align__(16) short smem[16384];

    const int tid = threadIdx.x;
    const int w = tid >> 6, l = tid & 63;
    const int lr = l & 15, lg = l >> 4;

    const int bid = blockIdx.x;
    const int p  = bid >> 6;          // pair 0..15
    const int bh = bid & 63;          // (b,h); bid%8 == bh%8 -> per-(b,h) XCD
    const int h = bh & 15, b = bh >> 4;
    const size_t bT = (size_t)b * T_SEQ;

    // staging granule geometry: issues i=0,1 -> granule g = w*128 + i*64 + l
    const int g0 = w * 128 + l, g1 = g0 + 64;
    const int rg0 = g0 >> 3, rg1 = g1 >> 3;                    // LDS row 0..63
    const int sc0 = (g0 & 7) ^ (rg0 & 7), sc1 = (g1 & 7) ^ (rg1 & 7);  // swizzled chunk
    short* const dst0 = &smem[(w * 128) * 8];
    short* const dst1 = &smem[(w * 128 + 64) * 8];

    // global source bases (row rg, swizzle-chunk sc pre-applied)
    const size_t koff0 = (bT + rg0) * 2048 + 1024 + h * DHEAD + sc0 * 8;
    const size_t koff1 = (bT + rg1) * 2048 + 1024 + h * DHEAD + sc1 * 8;
    const short* const pKh0 = qkhi + koff0;
    const short* const pKh1 = qkhi + koff1;
    const short* const pKl0 = qklo + koff0;
    const short* const pKl1 = qklo + koff1;
    const short* const pV0 = vt + ((size_t)((b * NHEAD + h) * DHEAD) + rg0) * T_SEQ + sc0 * 8;
    const short* const pV1 = vt + ((size_t)((b * NHEAD + h) * DHEAD) + rg1) * T_SEQ + sc1 * 8;

    for (int half = 0; half < 2; ++half) {
        const int xi = half ? (31 - p) : p;
        const int q0 = xi * 64;
        const int qw = q0 + w * 16;           // wave's 16 q-rows

        // Q fragments: direct bf16 loads (pre-scaled, pre-split)
        bf16x8 ahi[2], alo[2];
        #pragma unroll
        for (int kk = 0; kk < 2; ++kk) {
            size_t off = (bT + qw + lr) * 2048 + h * DHEAD + kk * 32 + lg * 8;
            ahi[kk] = *(const bf16x8*)(qkhi + off);
            alo[kk] = *(const bf16x8*)(qklo + off);
        }

        f32x4 O[4];
        #pragma unroll
        for (int dt = 0; dt < 4; ++dt)
            O[dt] = (f32x4){0.f, 0.f, 0.f, 0.f};
        float mrun[4], lrun[4];
        #pragma unroll
        for (int r = 0; r < 4; ++r) { mrun[r] = -3.0e38f; lrun[r] = 0.f; }

        const int nsteps = xi + 1;
        for (int t = 0; t < nsteps; ++t) {
            const int j0 = t * 64;
            __syncthreads();                 // prior-step readers done
            // stage K hi/lo + V for rows j0..j0+63 (pure DMA, no VALU)
            gload16(pKh0 + (size_t)j0 * 2048, dst0);
            gload16(pKh1 + (size_t)j0 * 2048, dst1);
            gload16(pKl0 + (size_t)j0 * 2048, dst0 + 4096);
            gload16(pKl1 + (size_t)j0 * 2048, dst1 + 4096);
            gload16(pV0 + j0, dst0 + 8192);
            gload16(pV1 + j0, dst1 + 8192);
            __syncthreads();                 // drains vmcnt -> tile ready

            f32x4 S[4];
            #pragma unroll
            for (int ct = 0; ct < 4; ++ct) {
                f32x4 s = (f32x4){0.f, 0.f, 0.f, 0.f};
                #pragma unroll
                for (int kk = 0; kk < 2; ++kk) {
                    int j  = ct * 16 + lr;
                    int ck = kk * 4 + lg;
                    int idx = j * 64 + ((ck ^ (j & 7)) << 3);
                    bf16x8 bh8 = *(bf16x8*)&smem[idx];
                    bf16x8 bl8 = *(bf16x8*)&smem[4096 + idx];
                    s = __builtin_amdgcn_mfma_f32_16x16x32_bf16(ahi[kk], bh8, s, 0, 0, 0);
                    s = __builtin_amdgcn_mfma_f32_16x16x32_bf16(alo[kk], bh8, s, 0, 0, 0);
                    s = __builtin_amdgcn_mfma_f32_16x16x32_bf16(ahi[kk], bl8, s, 0, 0, 0);
                }
                if (j0 + ct * 16 + 15 > qw) {   // diagonal / masked region
                    int jabs = j0 + ct * 16 + lr;
                    #pragma unroll
                    for (int r = 0; r < 4; ++r) {
                        int qabs = qw + lg * 4 + r;
                        s[r] = (jabs <= qabs) ? s[r] : -3.0e38f;
                    }
                }
                S[ct] = s;
            }

            float tm[4];
            #pragma unroll
            for (int r = 0; r < 4; ++r) {
                float v = fmaxf(fmaxf(S[0][r], S[1][r]), fmaxf(S[2][r], S[3][r]));
                v = fmaxf(v, __shfl_xor(v, 1));
                v = fmaxf(v, __shfl_xor(v, 2));
                v = fmaxf(v, __shfl_xor(v, 4));
                v = fmaxf(v, __shfl_xor(v, 8));
                tm[r] = v;
            }
            bool exceed = (tm[0] > mrun[0]) | (tm[1] > mrun[1]) |
                          (tm[2] > mrun[2]) | (tm[3] > mrun[3]);
            if (__any(exceed)) {   // rescale pass (exact skip otherwise)
                #pragma unroll
                for (int r = 0; r < 4; ++r) {
                    float mnew  = fmaxf(mrun[r], tm[r]);
                    float alpha = __builtin_amdgcn_exp2f(mrun[r] - mnew);
                    mrun[r] = mnew;
                    lrun[r] *= alpha;
                    #pragma unroll
                    for (int dt = 0; dt < 4; ++dt)
                        O[dt][r] *= alpha;
                }
            }

            // P = exp2(S - m) -> per-wave Ps region (16 rows x 64 cols)
            float lsum[4] = {0.f, 0.f, 0.f, 0.f};
            #pragma unroll
            for (int ct = 0; ct < 4; ++ct) {
                #pragma unroll
                for (int r = 0; r < 4; ++r) {
                    float pv = __builtin_amdgcn_exp2f(S[ct][r] - mrun[r]);
                    lsum[r] += pv;
                    int row = lg * 4 + r;              // 0..15
                    int col = ct * 16 + lr;
                    smem[12288 + w * 1024 + row * 64 + (col ^ ((row & 7) << 3))] = (short)f2bf(pv);
                }
            }
            #pragma unroll
            for (int r = 0; r < 4; ++r) {
                float s = lsum[r];
                s += __shfl_xor(s, 1);
                s += __shfl_xor(s, 2);
                s += __shfl_xor(s, 4);
                s += __shfl_xor(s, 8);
                lrun[r] += s;
            }

            __builtin_amdgcn_wave_barrier();  // order P writes before P reads

            // PV: O += P @ V
            bf16x8 pa[2];
            #pragma unroll
            for (int jk = 0; jk < 2; ++jk) {
                int ck = jk * 4 + lg;
                pa[jk] = *(bf16x8*)&smem[12288 + w * 1024 + lr * 64 + ((ck ^ (lr & 7)) << 3)];
            }
            #pragma unroll
            for (int dt = 0; dt < 4; ++dt) {
                #pragma unroll
                for (int jk = 0; jk < 2; ++jk) {
                    int d  = dt * 16 + lr;
                    int ck = jk * 4 + lg;
                    bf16x8 vb = *(bf16x8*)&smem[8192 + d * 64 + ((ck ^ (d & 7)) << 3)];
                    O[dt] = __builtin_amdgcn_mfma_f32_16x16x32_bf16(pa[jk], vb, O[dt], 0, 0, 0);
                }
            }
        }

        // Epilogue: O / l -> ctx bf16
        #pragma unroll
        for (int r = 0; r < 4; ++r) {
            float inv = 1.0f / lrun[r];
            int row = qw + lg * 4 + r;
            #pragma unroll
            for (int dt = 0; dt < 4; ++dt) {
                int col = h * DHEAD + dt * 16 + lr;
                ctxb[(size_t)(b * T_SEQ + row) * CEMB + col] = (short)f2bf(O[dt][r] * inv);
            }
        }
    }
}

// ---------------------------------------------------------------------------
extern "C" void kernel_launch(void* const* d_in, const int* in_sizes, int n_in,
                              void* d_out, int out_size, void* d_ws, size_t ws_size,
                              hipStream_t stream)
{
    const float* x    = (const float*)d_in[0];
    const float* Wqkv = (const float*)d_in[1];
    const float* bqkv = (const float*)d_in[2];
    const float* Wo   = (const float*)d_in[3];
    const float* bo   = (const float*)d_in[4];
    float* out = (float*)d_out;

    // Workspace (110 MB):
    char* ws = (char*)d_ws;
    short* qkhi = (short*)ws;                           // 32 MB [8192][2048] (late)
    short* vbuf = (short*)ws;                           // 16 MB [8192][1024] (early, dead before qk)
    short* qklo = (short*)(ws + (size_t)(32u << 20));   // 32 MB
    short* Vt   = (short*)(ws + (size_t)(64u << 20));   // 16 MB [B][H][64][T]
    short* ctxb = (short*)(ws + (size_t)(80u << 20));   // 16 MB [8192][1024]
    short* WhiT = (short*)(ws + (size_t)(96u << 20));   // 6 MB [3072][1024]
    short* WloT = (short*)(ws + (size_t)(102u << 20));  // 6 MB
    short* WoT  = (short*)(ws + (size_t)(108u << 20));  // 2 MB [1024][1024]

    // 1) weight transpose+split
    transpose_split_kernel<<<dim3(48, 16), 256, 0, stream>>>(Wqkv, 3 * CEMB, WhiT, WloT);
    transpose_split_kernel<<<dim3(16, 16), 256, 0, stream>>>(Wo, CEMB, WoT, nullptr);

    // 2) V = x @ Wv + bv  (bf16 out)
    gemm_mfma_kernel<1, true, 1><<<dim3(8, 64), 256, 0, stream>>>(
        x, nullptr, WhiT + (size_t)2048 * 1024, nullptr, bqkv + 2048, vbuf, nullptr, CEMB, CEMB);

    // 3) repack V -> Vt
    repack_vt_kernel<<<dim3(32, 16, 4), 256, 0, stream>>>(vbuf, Vt);

    // 4) qk = x @ Wqk + b  -> split hi/lo bf16, q cols pre-scaled (overwrites vbuf)
    gemm_mfma_kernel<3, true, 2><<<dim3(16, 64), 256, 0, stream>>>(
        x, nullptr, WhiT, WloT, bqkv, qkhi, qklo, CEMB, 2048);

    // 5) causal MFMA flash attention -> ctx bf16 (1024 work-uniform blocks)
    attn_mfma_kernel<<<dim3(1024), 256, 0, stream>>>(qkhi, qklo, Vt, ctxb);

    // 6) out = ctx @ Wo + bo  (fp32 out)
    gemm_mfma_kernel<1, false, 0><<<dim3(8, 64), 256, 0, stream>>>(
        nullptr, ctxb, WoT, nullptr, bo, out, nullptr, CEMB, CEMB);
}

// Round 9
// 374.491 us; speedup vs baseline: 1.2386x; 1.0268x over previous
//
#include <hip/hip_runtime.h>
#include <cstdint>
#include <cstddef>

// Problem constants: B=4, T=2048, C=1024, H=16, d=64
#define T_SEQ 2048
#define CEMB  1024
#define NHEAD 16
#define DHEAD 64

// q pre-scale: 32 (sqrt(C) quirk) * log2(e)  -> logits in log2 units
#define QSCALE 46.1662413084468f

typedef __attribute__((ext_vector_type(8))) short bf16x8;
typedef __attribute__((ext_vector_type(4))) float f32x4;

static __device__ __forceinline__ unsigned short f2bf(float x) {
    unsigned u = __builtin_bit_cast(unsigned, x);
    unsigned r = (u + 0x7FFFu + ((u >> 16) & 1u)) >> 16;
    return (unsigned short)r;
}
static __device__ __forceinline__ float bf2f(unsigned short b) {
    unsigned u = ((unsigned)b) << 16;
    return __builtin_bit_cast(float, u);
}

// async global->LDS: 16B per lane; ldsbase wave-uniform, lane offset = lane*16B.
static __device__ __forceinline__ void gload16(const short* gsrc, short* ldsbase) {
    __builtin_amdgcn_global_load_lds(
        (const __attribute__((address_space(1))) void*)gsrc,
        (__attribute__((address_space(3))) void*)ldsbase, 16, 0, 0);
}

// ---------------------------------------------------------------------------
// MFMA GEMM, 128x128 tile, BK=32, 256 threads (4 waves, 2x2).
//   C[M][N] = A[M][K] @ B^T[N][K]^T + bias[N]
// SPLIT==3: A,B split hi/lo bf16, 3 MFMAs (hh+lh+hl) -> ~fp32 product.
// A_F32: A read fp32, split in staging. Else A bf16 via global_load_lds.
// OUT_MODE: 0 = fp32, 1 = bf16, 2 = split hi/lo bf16 (cols<1024 scaled QSCALE).
// ---------------------------------------------------------------------------
template<int SPLIT, bool A_F32, int OUT_MODE>
__global__ __launch_bounds__(256) void gemm_mfma_kernel(
    const float* __restrict__ Af, const short* __restrict__ Ah,
    const short* __restrict__ Bh, const short* __restrict__ Bl,
    const float* __restrict__ bias,
    void* __restrict__ Cout, void* __restrict__ Cout2, int K, int ldc)
{
    __shared__ __align__(16) short smem[(SPLIT == 3) ? 16384 : 8192];

    const int tid = threadIdx.x;
    const int w = tid >> 6, l = tid & 63;
    const int lr = l & 15, lg = l >> 4;
    const int wr = w >> 1, wc = w & 1;
    const int row0 = blockIdx.y * 128;
    const int col0 = blockIdx.x * 128;

    f32x4 acc[4][4];
    #pragma unroll
    for (int mt = 0; mt < 4; ++mt)
        #pragma unroll
        for (int nt = 0; nt < 4; ++nt)
            acc[mt][nt] = (f32x4){0.f, 0.f, 0.f, 0.f};

    const int sB0 = w * 128 + l, sB1 = sB0 + 64;
    const short* gB0 = Bh + (size_t)(col0 + (sB0 & 127)) * K + (sB0 >> 7) * 8;
    const short* gB1 = Bh + (size_t)(col0 + (sB1 & 127)) * K + (sB1 >> 7) * 8;
    short* dB0 = &smem[4096 + (w * 128) * 8];
    short* dB1 = &smem[4096 + (w * 128 + 64) * 8];
    const short* gBl0 = nullptr; const short* gBl1 = nullptr;
    if constexpr (SPLIT == 3) {
        gBl0 = Bl + (size_t)(col0 + (sB0 & 127)) * K + (sB0 >> 7) * 8;
        gBl1 = Bl + (size_t)(col0 + (sB1 & 127)) * K + (sB1 >> 7) * 8;
    }
    const short* gA0 = nullptr; const short* gA1 = nullptr;
    if constexpr (!A_F32) {
        gA0 = Ah + (size_t)(row0 + (sB0 & 127)) * K + (sB0 >> 7) * 8;
        gA1 = Ah + (size_t)(row0 + (sB1 & 127)) * K + (sB1 >> 7) * 8;
    }
    short* dA0 = &smem[(w * 128) * 8];
    short* dA1 = &smem[(w * 128 + 64) * 8];

    const int arow = tid >> 1, ahalf = tid & 1;
    const float* gAf = A_F32 ? (Af + (size_t)(row0 + arow) * K + ahalf * 16) : nullptr;

    for (int kt = 0; kt < K; kt += 32) {
        __syncthreads();
        if constexpr (!A_F32) {
            gload16(gA0 + kt, dA0);
            gload16(gA1 + kt, dA1);
        }
        gload16(gB0 + kt, dB0);
        gload16(gB1 + kt, dB1);
        if constexpr (SPLIT == 3) {
            gload16(gBl0 + kt, &smem[12288 + (w * 128) * 8]);
            gload16(gBl1 + kt, &smem[12288 + (w * 128 + 64) * 8]);
        }
        if constexpr (A_F32) {
            const float* src = gAf + kt;
            float4 f0 = *(const float4*)(src);
            float4 f1 = *(const float4*)(src + 4);
            float4 f2 = *(const float4*)(src + 8);
            float4 f3 = *(const float4*)(src + 12);
            float xs[16] = {f0.x, f0.y, f0.z, f0.w, f1.x, f1.y, f1.z, f1.w,
                            f2.x, f2.y, f2.z, f2.w, f3.x, f3.y, f3.z, f3.w};
            #pragma unroll
            for (int q = 0; q < 2; ++q) {
                bf16x8 h8, l8;
                #pragma unroll
                for (int e = 0; e < 8; ++e) {
                    float x = xs[q * 8 + e];
                    if constexpr (SPLIT == 3) {
                        unsigned u = __builtin_bit_cast(unsigned, x);
                        h8[e] = (short)(unsigned short)(u >> 16);
                        float hf = __builtin_bit_cast(float, u & 0xFFFF0000u);
                        l8[e] = (short)f2bf(x - hf);
                    } else {
                        h8[e] = (short)f2bf(x);
                    }
                }
                int slot = (ahalf * 2 + q) * 128 + arow;
                *(bf16x8*)&smem[slot * 8] = h8;
                if constexpr (SPLIT == 3) *(bf16x8*)&smem[8192 + slot * 8] = l8;
            }
        }
        __syncthreads();

        const int aoff = (lg * 128 + wr * 64 + lr) * 8;
        const int boff = 4096 + (lg * 128 + wc * 64 + lr) * 8;
        bf16x8 ahf[4], alf[4];
        #pragma unroll
        for (int mt = 0; mt < 4; ++mt) {
            ahf[mt] = *(const bf16x8*)&smem[aoff + mt * 128];
            if constexpr (SPLIT == 3)
                alf[mt] = *(const bf16x8*)&smem[8192 + aoff + mt * 128];
        }
        #pragma unroll
        for (int nt = 0; nt < 4; ++nt) {
            bf16x8 bhf = *(const bf16x8*)&smem[boff + nt * 128];
            if constexpr (SPLIT == 3) {
                bf16x8 blf = *(const bf16x8*)&smem[8192 + boff + nt * 128];
                #pragma unroll
                for (int mt = 0; mt < 4; ++mt) {
                    acc[mt][nt] = __builtin_amdgcn_mfma_f32_16x16x32_bf16(ahf[mt], bhf, acc[mt][nt], 0, 0, 0);
                    acc[mt][nt] = __builtin_amdgcn_mfma_f32_16x16x32_bf16(alf[mt], bhf, acc[mt][nt], 0, 0, 0);
                    acc[mt][nt] = __builtin_amdgcn_mfma_f32_16x16x32_bf16(ahf[mt], blf, acc[mt][nt], 0, 0, 0);
                }
            } else {
                #pragma unroll
                for (int mt = 0; mt < 4; ++mt)
                    acc[mt][nt] = __builtin_amdgcn_mfma_f32_16x16x32_bf16(ahf[mt], bhf, acc[mt][nt], 0, 0, 0);
            }
        }
    }

    #pragma unroll
    for (int mt = 0; mt < 4; ++mt) {
        #pragma unroll
        for (int r = 0; r < 4; ++r) {
            int m = row0 + wr * 64 + mt * 16 + lg * 4 + r;
            #pragma unroll
            for (int nt = 0; nt < 4; ++nt) {
                int n = col0 + wc * 64 + nt * 16 + lr;
                float v = acc[mt][nt][r] + bias[n];
                if constexpr (OUT_MODE == 0) {
                    ((float*)Cout)[(size_t)m * ldc + n] = v;
                } else if constexpr (OUT_MODE == 1) {
                    ((short*)Cout)[(size_t)m * ldc + n] = (short)f2bf(v);
                } else {
                    if (n < 1024) v *= QSCALE;
                    unsigned u = __builtin_bit_cast(unsigned, v);
                    ((short*)Cout)[(size_t)m * ldc + n] = (short)(unsigned short)(u >> 16);
                    float hf = __builtin_bit_cast(float, u & 0xFFFF0000u);
                    ((short*)Cout2)[(size_t)m * ldc + n] = (short)f2bf(v - hf);
                }
            }
        }
    }
}

// ---------------------------------------------------------------------------
// Transpose + hi/lo bf16 split: src fp32 [Krows][nsrc] -> hi/lo [N][1024]
// ---------------------------------------------------------------------------
__global__ __launch_bounds__(256) void transpose_split_kernel(
    const float* __restrict__ src, int nsrc,
    short* __restrict__ hi, short* __restrict__ lo)
{
    __shared__ float tile[64][68];
    const int tid = threadIdx.x;
    const int n0 = blockIdx.x * 64, k0 = blockIdx.y * 64;
    {
        int kr = tid >> 2, cg = tid & 3;
        const float* s = src + (size_t)(k0 + kr) * nsrc + n0 + cg * 16;
        #pragma unroll
        for (int q = 0; q < 4; ++q) {
            float4 f = *(const float4*)(s + q * 4);
            tile[kr][cg * 16 + q * 4 + 0] = f.x;
            tile[kr][cg * 16 + q * 4 + 1] = f.y;
            tile[kr][cg * 16 + q * 4 + 2] = f.z;
            tile[kr][cg * 16 + q * 4 + 3] = f.w;
        }
    }
    __syncthreads();
    {
        int nr = tid >> 2, kg = tid & 3;
        int n = n0 + nr;
        bf16x8 h0, h1, lo0, lo1;
        #pragma unroll
        for (int e = 0; e < 8; ++e) {
            float a = tile[kg * 16 + e][nr];
            float b = tile[kg * 16 + 8 + e][nr];
            unsigned short ha = f2bf(a), hb = f2bf(b);
            h0[e] = (short)ha; h1[e] = (short)hb;
            lo0[e] = (short)f2bf(a - bf2f(ha));
            lo1[e] = (short)f2bf(b - bf2f(hb));
        }
        short* dh = hi + (size_t)n * 1024 + k0 + kg * 16;
        *(bf16x8*)dh = h0;
        *(bf16x8*)(dh + 8) = h1;
        if (lo) {
            short* dl = lo + (size_t)n * 1024 + k0 + kg * 16;
            *(bf16x8*)dl = lo0;
            *(bf16x8*)(dl + 8) = lo1;
        }
    }
}

// ---------------------------------------------------------------------------
// Repack V: v bf16 [B*T][C] -> Vt bf16 [B][H][64][T]
// ---------------------------------------------------------------------------
__global__ __launch_bounds__(256) void repack_vt_kernel(
    const short* __restrict__ v, short* __restrict__ vt)
{
    __shared__ short tile[64][80];
    const int tid = threadIdx.x;
    const int tt = blockIdx.x, h = blockIdx.y, b = blockIdx.z;
    const int t0 = tt * 64;
    {
        int tr = tid >> 2, cgrp = tid & 3;
        const short* src = v + (size_t)(b * T_SEQ + t0 + tr) * CEMB + h * DHEAD + cgrp * 16;
        *(bf16x8*)&tile[tr][cgrp * 16]     = *(const bf16x8*)src;
        *(bf16x8*)&tile[tr][cgrp * 16 + 8] = *(const bf16x8*)(src + 8);
    }
    __syncthreads();
    {
        int d = tid >> 2, tc = tid & 3;
        short s[16];
        #pragma unroll
        for (int e = 0; e < 16; ++e) s[e] = tile[tc * 16 + e][d];
        short* dst = vt + ((size_t)((b * NHEAD + h) * DHEAD + d)) * T_SEQ + t0 + tc * 16;
        bf16x8 v0, v1;
        #pragma unroll
        for (int e = 0; e < 8; ++e) { v0[e] = s[e]; v1[e] = s[8 + e]; }
        *(bf16x8*)dst       = v0;
        *(bf16x8*)(dst + 8) = v1;
    }
}

// ---------------------------------------------------------------------------
// MFMA flash attention (causal). Inputs pre-split bf16:
//  - qkhi/qklo [B*T][2048]: q cols 0..1023 (pre-scaled by 32*log2e), k cols 1024..2047
//  - Vt bf16 [B][H][64][T]; output ctx bf16 [B*T][1024]
// 64-row q-tiles paired (xi, 31-xi) -> every block exactly 33 KV-steps.
// Grid 1024, 4 blocks/CU; bid%8 = bh%8 keeps each (b,h) on one XCD.
// R9: T14 async-stage — tile t+1 loaded into REGISTERS at top of step t
// (latency hides under compute), ds_write after barrier; single 32 KB LDS.
// Deferred l-reduction (per-lane partials, one shfl chain at epilogue).
// P -> bf16 by truncation. exp2-domain softmax, exact defer-rescale.
// ---------------------------------------------------------------------------
__global__ __launch_bounds__(256, 4) void attn_mfma_kernel(
    const short* __restrict__ qkhi, const short* __restrict__ qklo,
    const short* __restrict__ vt, short* __restrict__ ctxb)
{
    // shorts: Khi @0 (4096), Klo @4096, Vs @8192, Ps @12288 (4096) = 32768 B
    __shared__ __align__(16) short smem[16384];

    const int tid = threadIdx.x;
    const int w = tid >> 6, l = tid & 63;
    const int lr = l & 15, lg = l >> 4;

    const int bid = blockIdx.x;
    const int p  = bid >> 6;          // pair 0..15
    const int bh = bid & 63;          // (b,h); bid%8 == bh%8 -> per-(b,h) XCD
    const int h = bh & 15, b = bh >> 4;
    const size_t bT = (size_t)b * T_SEQ;

    // ---- reg-staging geometry: thread covers rows rA/rB, chunk sc (swizzled src)
    const int rA = tid >> 3, rB = rA + 32;
    const int sc = (tid & 7) ^ (rA & 7);
    const size_t kA = (bT + rA) * 2048 + 1024 + h * DHEAD + sc * 8;
    const size_t kB = (bT + rB) * 2048 + 1024 + h * DHEAD + sc * 8;
    const short* const bKhA = qkhi + kA;
    const short* const bKhB = qkhi + kB;
    const short* const bKlA = qklo + kA;
    const short* const bKlB = qklo + kB;
    const size_t vtb = (size_t)((b * NHEAD + h) * DHEAD);
    const short* const bVA = vt + (vtb + rA) * T_SEQ + sc * 8;
    const short* const bVB = vt + (vtb + rB) * T_SEQ + sc * 8;

    bf16x8 stg[6];
    #define LOADR(jt) do {                                                \
        size_t ko = (size_t)(jt) * 131072; int vo = (jt) * 64;            \
        stg[0] = *(const bf16x8*)(bKhA + ko);                             \
        stg[1] = *(const bf16x8*)(bKhB + ko);                             \
        stg[2] = *(const bf16x8*)(bKlA + ko);                             \
        stg[3] = *(const bf16x8*)(bKlB + ko);                             \
        stg[4] = *(const bf16x8*)(bVA + vo);                              \
        stg[5] = *(const bf16x8*)(bVB + vo);                              \
    } while (0)
    #define WRITER() do {                                                 \
        *(bf16x8*)&smem[tid * 8]         = stg[0];                        \
        *(bf16x8*)&smem[tid * 8 + 2048]  = stg[1];                        \
        *(bf16x8*)&smem[tid * 8 + 4096]  = stg[2];                        \
        *(bf16x8*)&smem[tid * 8 + 6144]  = stg[3];                        \
        *(bf16x8*)&smem[tid * 8 + 8192]  = stg[4];                        \
        *(bf16x8*)&smem[tid * 8 + 10240] = stg[5];                        \
    } while (0)

    for (int half = 0; half < 2; ++half) {
        const int xi = half ? (31 - p) : p;
        const int q0 = xi * 64;
        const int qw = q0 + w * 16;           // wave's 16 q-rows

        // prologue: stage tile 0 (exposed once per half)
        LOADR(0);
        __syncthreads();                      // prior half's readers done
        WRITER();

        // Q fragments: direct bf16 loads (pre-scaled, pre-split)
        bf16x8 ahi[2], alo[2];
        #pragma unroll
        for (int kk = 0; kk < 2; ++kk) {
            size_t off = (bT + qw + lr) * 2048 + h * DHEAD + kk * 32 + lg * 8;
            ahi[kk] = *(const bf16x8*)(qkhi + off);
            alo[kk] = *(const bf16x8*)(qklo + off);
        }

        f32x4 O[4];
        #pragma unroll
        for (int dt = 0; dt < 4; ++dt)
            O[dt] = (f32x4){0.f, 0.f, 0.f, 0.f};
        float mrun[4], lpart[4];
        #pragma unroll
        for (int r = 0; r < 4; ++r) { mrun[r] = -3.0e38f; lpart[r] = 0.f; }

        __syncthreads();                      // tile 0 visible

        const int nsteps = xi + 1;
        for (int t = 0; t < nsteps; ++t) {
            const int j0 = t * 64;
            const bool pf = (t + 1 < nsteps);
            if (pf) LOADR(t + 1);             // issue early; hides under compute

            f32x4 S[4];
            #pragma unroll
            for (int ct = 0; ct < 4; ++ct) {
                f32x4 s = (f32x4){0.f, 0.f, 0.f, 0.f};
                #pragma unroll
                for (int kk = 0; kk < 2; ++kk) {
                    int j  = ct * 16 + lr;
                    int ck = kk * 4 + lg;
                    int idx = j * 64 + ((ck ^ (j & 7)) << 3);
                    bf16x8 bh8 = *(bf16x8*)&smem[idx];
                    bf16x8 bl8 = *(bf16x8*)&smem[4096 + idx];
                    s = __builtin_amdgcn_mfma_f32_16x16x32_bf16(ahi[kk], bh8, s, 0, 0, 0);
                    s = __builtin_amdgcn_mfma_f32_16x16x32_bf16(alo[kk], bh8, s, 0, 0, 0);
                    s = __builtin_amdgcn_mfma_f32_16x16x32_bf16(ahi[kk], bl8, s, 0, 0, 0);
                }
                if (j0 + ct * 16 + 15 > qw) {   // diagonal / masked region
                    int jabs = j0 + ct * 16 + lr;
                    #pragma unroll
                    for (int r = 0; r < 4; ++r) {
                        int qabs = qw + lg * 4 + r;
                        s[r] = (jabs <= qabs) ? s[r] : -3.0e38f;
                    }
                }
                S[ct] = s;
            }

            float tm[4];
            #pragma unroll
            for (int r = 0; r < 4; ++r) {
                float v = fmaxf(fmaxf(S[0][r], S[1][r]), fmaxf(S[2][r], S[3][r]));
                v = fmaxf(v, __shfl_xor(v, 1));
                v = fmaxf(v, __shfl_xor(v, 2));
                v = fmaxf(v, __shfl_xor(v, 4));
                v = fmaxf(v, __shfl_xor(v, 8));
                tm[r] = v;
            }
            bool exceed = (tm[0] > mrun[0]) | (tm[1] > mrun[1]) |
                          (tm[2] > mrun[2]) | (tm[3] > mrun[3]);
            if (__any(exceed)) {   // rescale pass (exact skip otherwise)
                #pragma unroll
                for (int r = 0; r < 4; ++r) {
                    float mnew  = fmaxf(mrun[r], tm[r]);
                    float alpha = __builtin_amdgcn_exp2f(mrun[r] - mnew);
                    mrun[r] = mnew;
                    lpart[r] *= alpha;
                    #pragma unroll
                    for (int dt = 0; dt < 4; ++dt)
                        O[dt][r] *= alpha;
                }
            }

            // P = exp2(S - m) -> per-wave Ps (truncate to bf16); defer l-reduce
            #pragma unroll
            for (int ct = 0; ct < 4; ++ct) {
                #pragma unroll
                for (int r = 0; r < 4; ++r) {
                    float pv = __builtin_amdgcn_exp2f(S[ct][r] - mrun[r]);
                    lpart[r] += pv;
                    int row = lg * 4 + r;              // 0..15
                    int col = ct * 16 + lr;
                    smem[12288 + w * 1024 + row * 64 + (col ^ ((row & 7) << 3))] =
                        (short)(unsigned short)(__builtin_bit_cast(unsigned, pv) >> 16);
                }
            }

            __builtin_amdgcn_wave_barrier();  // order P writes before P reads

            // PV: O += P @ V
            bf16x8 pa[2];
            #pragma unroll
            for (int jk = 0; jk < 2; ++jk) {
                int ck = jk * 4 + lg;
                pa[jk] = *(bf16x8*)&smem[12288 + w * 1024 + lr * 64 + ((ck ^ (lr & 7)) << 3)];
            }
            #pragma unroll
            for (int dt = 0; dt < 4; ++dt) {
                #pragma unroll
                for (int jk = 0; jk < 2; ++jk) {
                    int d  = dt * 16 + lr;
                    int ck = jk * 4 + lg;
                    bf16x8 vb = *(bf16x8*)&smem[8192 + d * 64 + ((ck ^ (d & 7)) << 3)];
                    O[dt] = __builtin_amdgcn_mfma_f32_16x16x32_bf16(pa[jk], vb, O[dt], 0, 0, 0);
                }
            }

            __syncthreads();                  // all reads of tile t done
            if (pf) {
                WRITER();                     // implicit vmcnt wait on stg data
                __syncthreads();              // tile t+1 visible
            }
        }

        // Epilogue: reduce lpart across lr, then O / l -> ctx bf16
        #pragma unroll
        for (int r = 0; r < 4; ++r) {
            float s = lpart[r];
            s += __shfl_xor(s, 1);
            s += __shfl_xor(s, 2);
            s += __shfl_xor(s, 4);
            s += __shfl_xor(s, 8);
            float inv = 1.0f / s;
            int row = qw + lg * 4 + r;
            #pragma unroll
            for (int dt = 0; dt < 4; ++dt) {
                int col = h * DHEAD + dt * 16 + lr;
                ctxb[(size_t)(b * T_SEQ + row) * CEMB + col] = (short)f2bf(O[dt][r] * inv);
            }
        }
    }
    #undef LOADR
    #undef WRITER
}

// ---------------------------------------------------------------------------
extern "C" void kernel_launch(void* const* d_in, const int* in_sizes, int n_in,
                              void* d_out, int out_size, void* d_ws, size_t ws_size,
                              hipStream_t stream)
{
    const float* x    = (const float*)d_in[0];
    const float* Wqkv = (const float*)d_in[1];
    const float* bqkv = (const float*)d_in[2];
    const float* Wo   = (const float*)d_in[3];
    const float* bo   = (const float*)d_in[4];
    float* out = (float*)d_out;

    // Workspace (110 MB):
    char* ws = (char*)d_ws;
    short* qkhi = (short*)ws;                           // 32 MB [8192][2048] (late)
    short* vbuf = (short*)ws;                           // 16 MB [8192][1024] (early, dead before qk)
    short* qklo = (short*)(ws + (size_t)(32u << 20));   // 32 MB
    short* Vt   = (short*)(ws + (size_t)(64u << 20));   // 16 MB [B][H][64][T]
    short* ctxb = (short*)(ws + (size_t)(80u << 20));   // 16 MB [8192][1024]
    short* WhiT = (short*)(ws + (size_t)(96u << 20));   // 6 MB [3072][1024]
    short* WloT = (short*)(ws + (size_t)(102u << 20));  // 6 MB
    short* WoT  = (short*)(ws + (size_t)(108u << 20));  // 2 MB [1024][1024]

    // 1) weight transpose+split
    transpose_split_kernel<<<dim3(48, 16), 256, 0, stream>>>(Wqkv, 3 * CEMB, WhiT, WloT);
    transpose_split_kernel<<<dim3(16, 16), 256, 0, stream>>>(Wo, CEMB, WoT, nullptr);

    // 2) V = x @ Wv + bv  (bf16 out)
    gemm_mfma_kernel<1, true, 1><<<dim3(8, 64), 256, 0, stream>>>(
        x, nullptr, WhiT + (size_t)2048 * 1024, nullptr, bqkv + 2048, vbuf, nullptr, CEMB, CEMB);

    // 3) repack V -> Vt
    repack_vt_kernel<<<dim3(32, 16, 4), 256, 0, stream>>>(vbuf, Vt);

    // 4) qk = x @ Wqk + b  -> split hi/lo bf16, q cols pre-scaled (overwrites vbuf)
    gemm_mfma_kernel<3, true, 2><<<dim3(16, 64), 256, 0, stream>>>(
        x, nullptr, WhiT, WloT, bqkv, qkhi, qklo, CEMB, 2048);

    // 5) causal MFMA flash attention -> ctx bf16 (1024 work-uniform blocks)
    attn_mfma_kernel<<<dim3(1024), 256, 0, stream>>>(qkhi, qklo, Vt, ctxb);

    // 6) out = ctx @ Wo + bo  (fp32 out)
    gemm_mfma_kernel<1, false, 0><<<dim3(8, 64), 256, 0, stream>>>(
        nullptr, ctxb, WoT, nullptr, bo, out, nullptr, CEMB, CEMB);
}

// Round 10
// 348.934 us; speedup vs baseline: 1.3294x; 1.0732x over previous
//
#include <hip/hip_runtime.h>
#include <cstdint>
#include <cstddef>

// Problem constants: B=4, T=2048, C=1024, H=16, d=64
#define T_SEQ 2048
#define CEMB  1024
#define NHEAD 16
#define DHEAD 64

// q pre-scale: 32 (sqrt(C) quirk) * log2(e)  -> logits in log2 units
#define QSCALE 46.1662413084468f

typedef __attribute__((ext_vector_type(8))) short bf16x8;
typedef __attribute__((ext_vector_type(4))) float f32x4;

static __device__ __forceinline__ unsigned short f2bf(float x) {
    unsigned u = __builtin_bit_cast(unsigned, x);
    unsigned r = (u + 0x7FFFu + ((u >> 16) & 1u)) >> 16;
    return (unsigned short)r;
}
static __device__ __forceinline__ float bf2f(unsigned short b) {
    unsigned u = ((unsigned)b) << 16;
    return __builtin_bit_cast(float, u);
}

// async global->LDS: 16B per lane; ldsbase wave-uniform, lane offset = lane*16B.
static __device__ __forceinline__ void gload16(const short* gsrc, short* ldsbase) {
    __builtin_amdgcn_global_load_lds(
        (const __attribute__((address_space(1))) void*)gsrc,
        (__attribute__((address_space(3))) void*)ldsbase, 16, 0, 0);
}

// ---------------------------------------------------------------------------
// MFMA GEMM, 128x128 tile, BK=32, 256 threads (4 waves, 2x2).
//   C[M][N] = A[M][K] @ B^T[N][K]^T + bias[N]
// SPLIT==3: A,B split hi/lo bf16, 3 MFMAs (hh+lh+hl) -> ~fp32 product.
// A_F32: A read fp32, split in staging. Else A bf16 via global_load_lds.
// OUT_MODE: 0 = fp32, 1 = bf16, 2 = split hi/lo bf16 (cols<1024 scaled QSCALE).
// ---------------------------------------------------------------------------
template<int SPLIT, bool A_F32, int OUT_MODE>
__global__ __launch_bounds__(256) void gemm_mfma_kernel(
    const float* __restrict__ Af, const short* __restrict__ Ah,
    const short* __restrict__ Bh, const short* __restrict__ Bl,
    const float* __restrict__ bias,
    void* __restrict__ Cout, void* __restrict__ Cout2, int K, int ldc)
{
    __shared__ __align__(16) short smem[(SPLIT == 3) ? 16384 : 8192];

    const int tid = threadIdx.x;
    const int w = tid >> 6, l = tid & 63;
    const int lr = l & 15, lg = l >> 4;
    const int wr = w >> 1, wc = w & 1;
    const int row0 = blockIdx.y * 128;
    const int col0 = blockIdx.x * 128;

    f32x4 acc[4][4];
    #pragma unroll
    for (int mt = 0; mt < 4; ++mt)
        #pragma unroll
        for (int nt = 0; nt < 4; ++nt)
            acc[mt][nt] = (f32x4){0.f, 0.f, 0.f, 0.f};

    const int sB0 = w * 128 + l, sB1 = sB0 + 64;
    const short* gB0 = Bh + (size_t)(col0 + (sB0 & 127)) * K + (sB0 >> 7) * 8;
    const short* gB1 = Bh + (size_t)(col0 + (sB1 & 127)) * K + (sB1 >> 7) * 8;
    short* dB0 = &smem[4096 + (w * 128) * 8];
    short* dB1 = &smem[4096 + (w * 128 + 64) * 8];
    const short* gBl0 = nullptr; const short* gBl1 = nullptr;
    if constexpr (SPLIT == 3) {
        gBl0 = Bl + (size_t)(col0 + (sB0 & 127)) * K + (sB0 >> 7) * 8;
        gBl1 = Bl + (size_t)(col0 + (sB1 & 127)) * K + (sB1 >> 7) * 8;
    }
    const short* gA0 = nullptr; const short* gA1 = nullptr;
    if constexpr (!A_F32) {
        gA0 = Ah + (size_t)(row0 + (sB0 & 127)) * K + (sB0 >> 7) * 8;
        gA1 = Ah + (size_t)(row0 + (sB1 & 127)) * K + (sB1 >> 7) * 8;
    }
    short* dA0 = &smem[(w * 128) * 8];
    short* dA1 = &smem[(w * 128 + 64) * 8];

    const int arow = tid >> 1, ahalf = tid & 1;
    const float* gAf = A_F32 ? (Af + (size_t)(row0 + arow) * K + ahalf * 16) : nullptr;

    for (int kt = 0; kt < K; kt += 32) {
        __syncthreads();
        if constexpr (!A_F32) {
            gload16(gA0 + kt, dA0);
            gload16(gA1 + kt, dA1);
        }
        gload16(gB0 + kt, dB0);
        gload16(gB1 + kt, dB1);
        if constexpr (SPLIT == 3) {
            gload16(gBl0 + kt, &smem[12288 + (w * 128) * 8]);
            gload16(gBl1 + kt, &smem[12288 + (w * 128 + 64) * 8]);
        }
        if constexpr (A_F32) {
            const float* src = gAf + kt;
            float4 f0 = *(const float4*)(src);
            float4 f1 = *(const float4*)(src + 4);
            float4 f2 = *(const float4*)(src + 8);
            float4 f3 = *(const float4*)(src + 12);
            float xs[16] = {f0.x, f0.y, f0.z, f0.w, f1.x, f1.y, f1.z, f1.w,
                            f2.x, f2.y, f2.z, f2.w, f3.x, f3.y, f3.z, f3.w};
            #pragma unroll
            for (int q = 0; q < 2; ++q) {
                bf16x8 h8, l8;
                #pragma unroll
                for (int e = 0; e < 8; ++e) {
                    float x = xs[q * 8 + e];
                    if constexpr (SPLIT == 3) {
                        unsigned u = __builtin_bit_cast(unsigned, x);
                        h8[e] = (short)(unsigned short)(u >> 16);
                        float hf = __builtin_bit_cast(float, u & 0xFFFF0000u);
                        l8[e] = (short)f2bf(x - hf);
                    } else {
                        h8[e] = (short)f2bf(x);
                    }
                }
                int slot = (ahalf * 2 + q) * 128 + arow;
                *(bf16x8*)&smem[slot * 8] = h8;
                if constexpr (SPLIT == 3) *(bf16x8*)&smem[8192 + slot * 8] = l8;
            }
        }
        __syncthreads();

        const int aoff = (lg * 128 + wr * 64 + lr) * 8;
        const int boff = 4096 + (lg * 128 + wc * 64 + lr) * 8;
        bf16x8 ahf[4], alf[4];
        #pragma unroll
        for (int mt = 0; mt < 4; ++mt) {
            ahf[mt] = *(const bf16x8*)&smem[aoff + mt * 128];
            if constexpr (SPLIT == 3)
                alf[mt] = *(const bf16x8*)&smem[8192 + aoff + mt * 128];
        }
        #pragma unroll
        for (int nt = 0; nt < 4; ++nt) {
            bf16x8 bhf = *(const bf16x8*)&smem[boff + nt * 128];
            if constexpr (SPLIT == 3) {
                bf16x8 blf = *(const bf16x8*)&smem[8192 + boff + nt * 128];
                #pragma unroll
                for (int mt = 0; mt < 4; ++mt) {
                    acc[mt][nt] = __builtin_amdgcn_mfma_f32_16x16x32_bf16(ahf[mt], bhf, acc[mt][nt], 0, 0, 0);
                    acc[mt][nt] = __builtin_amdgcn_mfma_f32_16x16x32_bf16(alf[mt], bhf, acc[mt][nt], 0, 0, 0);
                    acc[mt][nt] = __builtin_amdgcn_mfma_f32_16x16x32_bf16(ahf[mt], blf, acc[mt][nt], 0, 0, 0);
                }
            } else {
                #pragma unroll
                for (int mt = 0; mt < 4; ++mt)
                    acc[mt][nt] = __builtin_amdgcn_mfma_f32_16x16x32_bf16(ahf[mt], bhf, acc[mt][nt], 0, 0, 0);
            }
        }
    }

    #pragma unroll
    for (int mt = 0; mt < 4; ++mt) {
        #pragma unroll
        for (int r = 0; r < 4; ++r) {
            int m = row0 + wr * 64 + mt * 16 + lg * 4 + r;
            #pragma unroll
            for (int nt = 0; nt < 4; ++nt) {
                int n = col0 + wc * 64 + nt * 16 + lr;
                float v = acc[mt][nt][r] + bias[n];
                if constexpr (OUT_MODE == 0) {
                    ((float*)Cout)[(size_t)m * ldc + n] = v;
                } else if constexpr (OUT_MODE == 1) {
                    ((short*)Cout)[(size_t)m * ldc + n] = (short)f2bf(v);
                } else {
                    if (n < 1024) v *= QSCALE;
                    unsigned u = __builtin_bit_cast(unsigned, v);
                    ((short*)Cout)[(size_t)m * ldc + n] = (short)(unsigned short)(u >> 16);
                    float hf = __builtin_bit_cast(float, u & 0xFFFF0000u);
                    ((short*)Cout2)[(size_t)m * ldc + n] = (short)f2bf(v - hf);
                }
            }
        }
    }
}

// ---------------------------------------------------------------------------
// Transpose + hi/lo bf16 split: src fp32 [Krows][nsrc] -> hi/lo [N][1024]
// ---------------------------------------------------------------------------
__global__ __launch_bounds__(256) void transpose_split_kernel(
    const float* __restrict__ src, int nsrc,
    short* __restrict__ hi, short* __restrict__ lo)
{
    __shared__ float tile[64][68];
    const int tid = threadIdx.x;
    const int n0 = blockIdx.x * 64, k0 = blockIdx.y * 64;
    {
        int kr = tid >> 2, cg = tid & 3;
        const float* s = src + (size_t)(k0 + kr) * nsrc + n0 + cg * 16;
        #pragma unroll
        for (int q = 0; q < 4; ++q) {
            float4 f = *(const float4*)(s + q * 4);
            tile[kr][cg * 16 + q * 4 + 0] = f.x;
            tile[kr][cg * 16 + q * 4 + 1] = f.y;
            tile[kr][cg * 16 + q * 4 + 2] = f.z;
            tile[kr][cg * 16 + q * 4 + 3] = f.w;
        }
    }
    __syncthreads();
    {
        int nr = tid >> 2, kg = tid & 3;
        int n = n0 + nr;
        bf16x8 h0, h1, lo0, lo1;
        #pragma unroll
        for (int e = 0; e < 8; ++e) {
            float a = tile[kg * 16 + e][nr];
            float b = tile[kg * 16 + 8 + e][nr];
            unsigned short ha = f2bf(a), hb = f2bf(b);
            h0[e] = (short)ha; h1[e] = (short)hb;
            lo0[e] = (short)f2bf(a - bf2f(ha));
            lo1[e] = (short)f2bf(b - bf2f(hb));
        }
        short* dh = hi + (size_t)n * 1024 + k0 + kg * 16;
        *(bf16x8*)dh = h0;
        *(bf16x8*)(dh + 8) = h1;
        if (lo) {
            short* dl = lo + (size_t)n * 1024 + k0 + kg * 16;
            *(bf16x8*)dl = lo0;
            *(bf16x8*)(dl + 8) = lo1;
        }
    }
}

// ---------------------------------------------------------------------------
// Repack V: v bf16 [B*T][C] -> Vt bf16 [B][H][64][T]
// ---------------------------------------------------------------------------
__global__ __launch_bounds__(256) void repack_vt_kernel(
    const short* __restrict__ v, short* __restrict__ vt)
{
    __shared__ short tile[64][80];
    const int tid = threadIdx.x;
    const int tt = blockIdx.x, h = blockIdx.y, b = blockIdx.z;
    const int t0 = tt * 64;
    {
        int tr = tid >> 2, cgrp = tid & 3;
        const short* src = v + (size_t)(b * T_SEQ + t0 + tr) * CEMB + h * DHEAD + cgrp * 16;
        *(bf16x8*)&tile[tr][cgrp * 16]     = *(const bf16x8*)src;
        *(bf16x8*)&tile[tr][cgrp * 16 + 8] = *(const bf16x8*)(src + 8);
    }
    __syncthreads();
    {
        int d = tid >> 2, tc = tid & 3;
        short s[16];
        #pragma unroll
        for (int e = 0; e < 16; ++e) s[e] = tile[tc * 16 + e][d];
        short* dst = vt + ((size_t)((b * NHEAD + h) * DHEAD + d)) * T_SEQ + t0 + tc * 16;
        bf16x8 v0, v1;
        #pragma unroll
        for (int e = 0; e < 8; ++e) { v0[e] = s[e]; v1[e] = s[8 + e]; }
        *(bf16x8*)dst       = v0;
        *(bf16x8*)(dst + 8) = v1;
    }
}

// ---------------------------------------------------------------------------
// MFMA flash attention (causal), SWAPPED QK^T layout.
//  - qkhi/qklo [B*T][2048]: q cols (pre-scaled by 32*log2e), k cols 1024..2047
//  - Vt bf16 [B][H][64][T]; output ctx bf16 [B*T][1024]
// S^T = mfma(K_frag, Q_frag): identical LDS/reg addressing, operands swapped.
// Lane (lr,lg) holds S[q = qw+lr][j = j0+ct*16+lg*4+r] -> softmax per q-row is
// lane-local: in-lane max over 16 + 2 shfl hops; m/l kept per lane (row lr);
// P packed to bf16 pairs, 4x ds_write_b64 (swizzled); PV unchanged (A=P).
// alpha broadcast to O rows via 4 __shfl only on rescale steps; l reduced once
// at epilogue. Staging: pure global_load_lds (zero VGPR), single 32 KB LDS.
// 64-row q-tiles paired (xi, 31-xi): every block exactly 33 KV-steps;
// grid 1024, bid%8 = bh%8 keeps each (b,h) on one XCD.
// ---------------------------------------------------------------------------
__global__ __launch_bounds__(256) void attn_mfma_kernel(
    const short* __restrict__ qkhi, const short* __restrict__ qklo,
    const short* __restrict__ vt, short* __restrict__ ctxb)
{
    // shorts: Khi @0 (4096), Klo @4096, Vs @8192, Ps @12288 (4096) = 32768 B
    __shared__ __align__(16) short smem[16384];

    const int tid = threadIdx.x;
    const int w = tid >> 6, l = tid & 63;
    const int lr = l & 15, lg = l >> 4;

    const int bid = blockIdx.x;
    const int p  = bid >> 6;          // pair 0..15
    const int bh = bid & 63;          // (b,h); bid%8 == bh%8 -> per-(b,h) XCD
    const int h = bh & 15, b = bh >> 4;
    const size_t bT = (size_t)b * T_SEQ;

    // staging granule geometry: issues i=0,1 -> granule g = w*128 + i*64 + l
    const int g0 = w * 128 + l, g1 = g0 + 64;
    const int rg0 = g0 >> 3, rg1 = g1 >> 3;                    // LDS row 0..63
    const int sc0 = (g0 & 7) ^ (rg0 & 7), sc1 = (g1 & 7) ^ (rg1 & 7);  // swizzled chunk
    short* const dst0 = &smem[(w * 128) * 8];
    short* const dst1 = &smem[(w * 128 + 64) * 8];

    const size_t koff0 = (bT + rg0) * 2048 + 1024 + h * DHEAD + sc0 * 8;
    const size_t koff1 = (bT + rg1) * 2048 + 1024 + h * DHEAD + sc1 * 8;
    const short* const pKh0 = qkhi + koff0;
    const short* const pKh1 = qkhi + koff1;
    const short* const pKl0 = qklo + koff0;
    const short* const pKl1 = qklo + koff1;
    const short* const pV0 = vt + ((size_t)((b * NHEAD + h) * DHEAD) + rg0) * T_SEQ + sc0 * 8;
    const short* const pV1 = vt + ((size_t)((b * NHEAD + h) * DHEAD) + rg1) * T_SEQ + sc1 * 8;

    // Ps addressing (per wave, 16 rows x 64 cols, 16B-chunk XOR swizzle)
    const int psBase = 12288 + w * 1024;
    const int pwChunk = (lg >> 1);           // with ct: chunk = ct*2 + (lg>>1)
    const int pwIntra = (lg & 1) * 4;        // 4-short offset inside chunk

    for (int half = 0; half < 2; ++half) {
        const int xi = half ? (31 - p) : p;
        const int q0 = xi * 64;
        const int qw = q0 + w * 16;           // wave's 16 q-rows

        // Q fragments (used as MFMA B operand now; same layout)
        bf16x8 qhi[2], qlo[2];
        #pragma unroll
        for (int kk = 0; kk < 2; ++kk) {
            size_t off = (bT + qw + lr) * 2048 + h * DHEAD + kk * 32 + lg * 8;
            qhi[kk] = *(const bf16x8*)(qkhi + off);
            qlo[kk] = *(const bf16x8*)(qklo + off);
        }

        f32x4 O[4];
        #pragma unroll
        for (int dt = 0; dt < 4; ++dt)
            O[dt] = (f32x4){0.f, 0.f, 0.f, 0.f};
        float mrow = -3.0e38f;   // running max for q-row lr (lane-local)
        float lrow = 0.f;        // running denom partial for q-row lr

        const int nsteps = xi + 1;
        for (int t = 0; t < nsteps; ++t) {
            const int j0 = t * 64;
            __syncthreads();                 // prior-step readers done
            gload16(pKh0 + (size_t)j0 * 2048, dst0);
            gload16(pKh1 + (size_t)j0 * 2048, dst1);
            gload16(pKl0 + (size_t)j0 * 2048, dst0 + 4096);
            gload16(pKl1 + (size_t)j0 * 2048, dst1 + 4096);
            gload16(pV0 + j0, dst0 + 8192);
            gload16(pV1 + j0, dst1 + 8192);
            __syncthreads();                 // drains vmcnt -> tile ready

            // ---- QK^T swapped: St[ct][r] = S[q=qw+lr][j0+ct*16+lg*4+r]
            f32x4 St[4];
            #pragma unroll
            for (int ct = 0; ct < 4; ++ct) {
                f32x4 s = (f32x4){0.f, 0.f, 0.f, 0.f};
                #pragma unroll
                for (int kk = 0; kk < 2; ++kk) {
                    int j  = ct * 16 + lr;             // A-frag row (k row in LDS)
                    int ck = kk * 4 + lg;
                    int idx = j * 64 + ((ck ^ (j & 7)) << 3);
                    bf16x8 kh8 = *(bf16x8*)&smem[idx];
                    bf16x8 kl8 = *(bf16x8*)&smem[4096 + idx];
                    s = __builtin_amdgcn_mfma_f32_16x16x32_bf16(kh8, qhi[kk], s, 0, 0, 0);
                    s = __builtin_amdgcn_mfma_f32_16x16x32_bf16(kh8, qlo[kk], s, 0, 0, 0);
                    s = __builtin_amdgcn_mfma_f32_16x16x32_bf16(kl8, qhi[kk], s, 0, 0, 0);
                }
                if (j0 + ct * 16 + 15 > qw) {          // diagonal / masked region
                    #pragma unroll
                    for (int r = 0; r < 4; ++r) {
                        int jabs = j0 + ct * 16 + lg * 4 + r;
                        int qabs = qw + lr;
                        s[r] = (jabs <= qabs) ? s[r] : -3.0e38f;
                    }
                }
                St[ct] = s;
            }

            // ---- softmax: per-lane row max (16 vals) + 2 shfl hops
            float tm = fmaxf(fmaxf(fmaxf(St[0][0], St[0][1]), fmaxf(St[0][2], St[0][3])),
                             fmaxf(fmaxf(St[1][0], St[1][1]), fmaxf(St[1][2], St[1][3])));
            tm = fmaxf(tm, fmaxf(fmaxf(fmaxf(St[2][0], St[2][1]), fmaxf(St[2][2], St[2][3])),
                                 fmaxf(fmaxf(St[3][0], St[3][1]), fmaxf(St[3][2], St[3][3]))));
            tm = fmaxf(tm, __shfl_xor(tm, 16));
            tm = fmaxf(tm, __shfl_xor(tm, 32));

            if (__any(tm > mrow)) {          // rescale pass (exact skip otherwise)
                float mnew  = fmaxf(mrow, tm);
                float alpha = __builtin_amdgcn_exp2f(mrow - mnew);
                mrow = mnew;
                lrow *= alpha;
                // broadcast alpha to this lane's O rows (lg*4+r)
                #pragma unroll
                for (int r = 0; r < 4; ++r) {
                    float aO = __shfl(alpha, lg * 4 + r);
                    #pragma unroll
                    for (int dt = 0; dt < 4; ++dt)
                        O[dt][r] *= aO;
                }
            }

            // ---- P = exp2(St - mrow), pack pairs, 4x ds_write_b64 (swizzled)
            #pragma unroll
            for (int ct = 0; ct < 4; ++ct) {
                float p0 = __builtin_amdgcn_exp2f(St[ct][0] - mrow);
                float p1 = __builtin_amdgcn_exp2f(St[ct][1] - mrow);
                float p2 = __builtin_amdgcn_exp2f(St[ct][2] - mrow);
                float p3 = __builtin_amdgcn_exp2f(St[ct][3] - mrow);
                lrow += (p0 + p1) + (p2 + p3);
                unsigned u0 = (__builtin_bit_cast(unsigned, p0) >> 16) |
                              (__builtin_bit_cast(unsigned, p1) & 0xFFFF0000u);
                unsigned u1 = (__builtin_bit_cast(unsigned, p2) >> 16) |
                              (__builtin_bit_cast(unsigned, p3) & 0xFFFF0000u);
                int chunk = ct * 2 + pwChunk;
                int sidx = psBase + lr * 64 + ((chunk ^ (lr & 7)) << 3) + pwIntra;
                uint2 uu; uu.x = u0; uu.y = u1;
                *(uint2*)&smem[sidx] = uu;
            }

            __builtin_amdgcn_wave_barrier();  // order P writes before P reads

            // ---- PV: O += P @ V   (A=P: row=lr=q-row; B=V: col=lr=d-col)
            bf16x8 pa[2];
            #pragma unroll
            for (int jk = 0; jk < 2; ++jk) {
                int ck = jk * 4 + lg;
                pa[jk] = *(bf16x8*)&smem[psBase + lr * 64 + ((ck ^ (lr & 7)) << 3)];
            }
            #pragma unroll
            for (int dt = 0; dt < 4; ++dt) {
                #pragma unroll
                for (int jk = 0; jk < 2; ++jk) {
                    int d  = dt * 16 + lr;
                    int ck = jk * 4 + lg;
                    bf16x8 vb = *(bf16x8*)&smem[8192 + d * 64 + ((ck ^ (d & 7)) << 3)];
                    O[dt] = __builtin_amdgcn_mfma_f32_16x16x32_bf16(pa[jk], vb, O[dt], 0, 0, 0);
                }
            }
        }

        // ---- Epilogue: reduce lrow (2 hops), broadcast to O rows, store
        float lsum = lrow + __shfl_xor(lrow, 16);
        lsum += __shfl_xor(lsum, 32);
        #pragma unroll
        for (int r = 0; r < 4; ++r) {
            float lO = __shfl(lsum, lg * 4 + r);
            float inv = 1.0f / lO;
            int row = qw + lg * 4 + r;
            #pragma unroll
            for (int dt = 0; dt < 4; ++dt) {
                int col = h * DHEAD + dt * 16 + lr;
                ctxb[(size_t)(b * T_SEQ + row) * CEMB + col] = (short)f2bf(O[dt][r] * inv);
            }
        }
    }
}

// ---------------------------------------------------------------------------
extern "C" void kernel_launch(void* const* d_in, const int* in_sizes, int n_in,
                              void* d_out, int out_size, void* d_ws, size_t ws_size,
                              hipStream_t stream)
{
    const float* x    = (const float*)d_in[0];
    const float* Wqkv = (const float*)d_in[1];
    const float* bqkv = (const float*)d_in[2];
    const float* Wo   = (const float*)d_in[3];
    const float* bo   = (const float*)d_in[4];
    float* out = (float*)d_out;

    // Workspace (110 MB):
    char* ws = (char*)d_ws;
    short* qkhi = (short*)ws;                           // 32 MB [8192][2048] (late)
    short* vbuf = (short*)ws;                           // 16 MB [8192][1024] (early, dead before qk)
    short* qklo = (short*)(ws + (size_t)(32u << 20));   // 32 MB
    short* Vt   = (short*)(ws + (size_t)(64u << 20));   // 16 MB [B][H][64][T]
    short* ctxb = (short*)(ws + (size_t)(80u << 20));   // 16 MB [8192][1024]
    short* WhiT = (short*)(ws + (size_t)(96u << 20));   // 6 MB [3072][1024]
    short* WloT = (short*)(ws + (size_t)(102u << 20));  // 6 MB
    short* WoT  = (short*)(ws + (size_t)(108u << 20));  // 2 MB [1024][1024]

    // 1) weight transpose+split
    transpose_split_kernel<<<dim3(48, 16), 256, 0, stream>>>(Wqkv, 3 * CEMB, WhiT, WloT);
    transpose_split_kernel<<<dim3(16, 16), 256, 0, stream>>>(Wo, CEMB, WoT, nullptr);

    // 2) V = x @ Wv + bv  (bf16 out)
    gemm_mfma_kernel<1, true, 1><<<dim3(8, 64), 256, 0, stream>>>(
        x, nullptr, WhiT + (size_t)2048 * 1024, nullptr, bqkv + 2048, vbuf, nullptr, CEMB, CEMB);

    // 3) repack V -> Vt
    repack_vt_kernel<<<dim3(32, 16, 4), 256, 0, stream>>>(vbuf, Vt);

    // 4) qk = x @ Wqk + b  -> split hi/lo bf16, q cols pre-scaled (overwrites vbuf)
    gemm_mfma_kernel<3, true, 2><<<dim3(16, 64), 256, 0, stream>>>(
        x, nullptr, WhiT, WloT, bqkv, qkhi, qklo, CEMB, 2048);

    // 5) causal MFMA flash attention -> ctx bf16 (1024 work-uniform blocks)
    attn_mfma_kernel<<<dim3(1024), 256, 0, stream>>>(qkhi, qklo, Vt, ctxb);

    // 6) out = ctx @ Wo + bo  (fp32 out)
    gemm_mfma_kernel<1, false, 0><<<dim3(8, 64), 256, 0, stream>>>(
        nullptr, ctxb, WoT, nullptr, bo, out, nullptr, CEMB, CEMB);
}